// Round 1
// baseline (499.649 us; speedup 1.0000x reference)
//
#include <hip/hip_runtime.h>
#include <hip/hip_bf16.h>
#include <math.h>

// Problem dims
#define T_ 30
#define B_ 32
#define V_ 32
#define F_ 128
#define L_ 256
#define LF_ 64
#define H_ 8
#define DH_ 16
#define HIST_ 10

// ---------- generic small transpose: out[c*rows+r] = in[r*cols+c] ----------
__global__ void k_transpose(const float* __restrict__ in, float* __restrict__ out,
                            int rows, int cols) {
    int idx = blockIdx.x * 256 + threadIdx.x;
    if (idx >= rows * cols) return;
    int r = idx / cols, c = idx % cols;
    out[c * rows + r] = in[idx];
}

// ---------- mask reduction: any over HIST -> 1.0/0.0 ----------
__global__ void k_mask(const int* __restrict__ m, float* __restrict__ mb) {
    int idx = blockIdx.x * 256 + threadIdx.x;
    if (idx >= B_ * L_) return;
    int any = 0;
#pragma unroll
    for (int h = 0; h < HIST_; ++h) any |= m[h * (B_ * L_) + idx];
    mb[idx] = any ? 1.0f : 0.0f;
}

__device__ inline float logsig(float x) {
    // stable log_sigmoid
    return (x >= 0.f) ? -log1pf(expf(-x)) : x - log1pf(expf(x));
}

// ---------- lane projections: kproj = lanes@Wk^T+bk ; lsv = logsig(lanes@Wv^T+bv)
// 8 lane-rows per block, 128 threads (one per output feature)
__global__ __launch_bounds__(128) void k_lanes(
    const float* __restrict__ lanes, const float* __restrict__ WkT,
    const float* __restrict__ bk, const float* __restrict__ WvT,
    const float* __restrict__ bv, float* __restrict__ kproj,
    float* __restrict__ lsv) {
    __shared__ float lrow[8][LF_];
    int f = threadIdx.x;
    int row0 = blockIdx.x * 8;
    for (int i = f; i < 8 * LF_; i += 128)
        lrow[i / LF_][i % LF_] = lanes[(size_t)row0 * LF_ + i];
    __syncthreads();
    float ak[8], av[8];
#pragma unroll
    for (int r = 0; r < 8; ++r) { ak[r] = 0.f; av[r] = 0.f; }
    for (int j = 0; j < LF_; ++j) {
        float wk = WkT[j * F_ + f], wv = WvT[j * F_ + f];
#pragma unroll
        for (int r = 0; r < 8; ++r) {
            float lj = lrow[r][j];
            ak[r] += lj * wk;
            av[r] += lj * wv;
        }
    }
    float bkf = bk[f], bvf = bv[f];
#pragma unroll
    for (int r = 0; r < 8; ++r) {
        size_t o = (size_t)(row0 + r) * F_ + f;
        kproj[o] = ak[r] + bkf;
        lsv[o]   = logsig(av[r] + bvf);
    }
}

// ---------- vehicle projections: q = 0.25*((veh+ip)@Wq^T+bq) ; r = (veh+ip)@Wr^T+br
__global__ __launch_bounds__(128) void k_qr(
    const float* __restrict__ veh, const float* __restrict__ ip,
    const float* __restrict__ WqT, const float* __restrict__ bq,
    const float* __restrict__ WrT, const float* __restrict__ br,
    float* __restrict__ qb, float* __restrict__ rb) {
    __shared__ float vrow[8][F_];
    int f = threadIdx.x;
    int row0 = blockIdx.x * 8;
    for (int i = f; i < 8 * F_; i += 128) {
        size_t g = (size_t)row0 * F_ + i;
        vrow[i / F_][i % F_] = veh[g] + ip[g];
    }
    __syncthreads();
    float aq[8], ar[8];
#pragma unroll
    for (int r = 0; r < 8; ++r) { aq[r] = 0.f; ar[r] = 0.f; }
    for (int j = 0; j < F_; ++j) {
        float wq = WqT[j * F_ + f], wr = WrT[j * F_ + f];
#pragma unroll
        for (int r = 0; r < 8; ++r) {
            float vj = vrow[r][j];
            aq[r] += vj * wq;
            ar[r] += vj * wr;
        }
    }
    float bqf = bq[f], brf = br[f];
#pragma unroll
    for (int r = 0; r < 8; ++r) {
        size_t o = (size_t)(row0 + r) * F_ + f;
        qb[o] = (aq[r] + bqf) * 0.25f;  // fold 1/sqrt(DH)
        rb[o] = ar[r] + brf;
    }
}

// ---------- attention: one block per (t,b,h); wave per query; writes ratt in
// [T,B,H,V,DH] flat order (the "raw reshape" layout)
__global__ __launch_bounds__(256) void k_attn(
    const float* __restrict__ kproj, const float* __restrict__ lsv,
    const float* __restrict__ maskb, const float* __restrict__ qbuf,
    const float* __restrict__ rbuf, float* __restrict__ ratt) {
    __shared__ float kL[L_ * 17];   // stride-17 pad: <=2-way bank conflicts
    __shared__ float vL[L_ * 17];
    __shared__ float mb[L_];
    __shared__ float pbuf[4][L_];

    int tid = threadIdx.x;
    int h = blockIdx.x % H_;
    int b = (blockIdx.x / H_) % B_;
    int t = blockIdx.x / (H_ * B_);

    const float* kbase = kproj + ((size_t)b * L_) * F_ + h * DH_;
    const float* vbase = lsv   + ((size_t)b * L_) * F_ + h * DH_;
    int d0 = tid & 15, l0 = tid >> 4;
    for (int c = 0; c < 16; ++c) {
        int l = c * 16 + l0;
        kL[l * 17 + d0] = kbase[(size_t)l * F_ + d0];
        vL[l * 17 + d0] = vbase[(size_t)l * F_ + d0];
    }
    mb[tid] = maskb[b * L_ + tid];
    __syncthreads();

    int lane = tid & 63, w = tid >> 6;
    size_t qrbase = ((size_t)t * B_ + b) * V_ * F_;

    for (int qi = 0; qi < 8; ++qi) {
        int v = w * 8 + qi;
        const float* qrow = qbuf + qrbase + (size_t)v * F_ + h * DH_;
        float qr[16];
#pragma unroll
        for (int d = 0; d < 16; ++d) qr[d] = qrow[d];

        float sc[4];
#pragma unroll
        for (int j = 0; j < 4; ++j) {
            int l = j * 64 + lane;
            float s = 0.f;
#pragma unroll
            for (int d = 0; d < 16; ++d) s += qr[d] * kL[l * 17 + d];
            sc[j] = (mb[l] > 0.5f) ? s : -1e9f;
        }
        // wave softmax over 256 entries (4/lane)
        float m = fmaxf(fmaxf(sc[0], sc[1]), fmaxf(sc[2], sc[3]));
        for (int off = 32; off; off >>= 1) m = fmaxf(m, __shfl_xor(m, off));
        float e0 = expf(sc[0] - m), e1 = expf(sc[1] - m);
        float e2 = expf(sc[2] - m), e3 = expf(sc[3] - m);
        float s_ = e0 + e1 + e2 + e3;
        for (int off = 32; off; off >>= 1) s_ += __shfl_xor(s_, off);
        float inv = 1.0f / s_;
        pbuf[w][0 * 64 + lane] = e0 * inv;
        pbuf[w][1 * 64 + lane] = e1 * inv;
        pbuf[w][2 * 64 + lane] = e2 * inv;
        pbuf[w][3 * 64 + lane] = e3 * inv;
        __syncthreads();

        // att[d] = exp( sum_l p[l]*lsv[l][d] ); lanes: d = lane&15, chunk = lane>>4
        int d = lane & 15, c4 = lane >> 4;
        float acc = 0.f;
        for (int i = 0; i < 64; ++i) {
            int l = c4 * 64 + i;
            acc += pbuf[w][l] * vL[l * 17 + d];
        }
        acc += __shfl_xor(acc, 16);
        acc += __shfl_xor(acc, 32);
        if (lane < 16) {
            float att = expf(acc);
            float rv = rbuf[qrbase + (size_t)v * F_ + h * DH_ + d];
            ratt[(((size_t)t * B_ + b) * H_ + h) * (V_ * DH_) + v * DH_ + d] = rv * att;
        }
        __syncthreads();
    }
}

// ---------- combine: out = ratt_flat @ Wc^T + bc + vehicles - initial_pos
__global__ __launch_bounds__(128) void k_out(
    const float* __restrict__ ratt, const float* __restrict__ WcT,
    const float* __restrict__ bc, const float* __restrict__ veh,
    const float* __restrict__ ip, float* __restrict__ out) {
    __shared__ float rr[8][F_];
    int f = threadIdx.x;
    int row0 = blockIdx.x * 8;
    for (int i = f; i < 8 * F_; i += 128)
        rr[i / F_][i % F_] = ratt[(size_t)row0 * F_ + i];
    __syncthreads();
    float acc[8];
#pragma unroll
    for (int r = 0; r < 8; ++r) acc[r] = 0.f;
    for (int j = 0; j < F_; ++j) {
        float wc = WcT[j * F_ + f];
#pragma unroll
        for (int r = 0; r < 8; ++r) acc[r] += rr[r][j] * wc;
    }
    float bcf = bc[f];
#pragma unroll
    for (int r = 0; r < 8; ++r) {
        size_t o = (size_t)(row0 + r) * F_ + f;
        out[o] = acc[r] + bcf + veh[o] - ip[o];
    }
}

extern "C" void kernel_launch(void* const* d_in, const int* in_sizes, int n_in,
                              void* d_out, int out_size, void* d_ws, size_t ws_size,
                              hipStream_t stream) {
    const float* vehicles    = (const float*)d_in[0];
    const float* initial_pos = (const float*)d_in[1];
    const float* lanes       = (const float*)d_in[2];
    const int*   mask        = (const int*)d_in[3];
    const float* Wk = (const float*)d_in[4];
    const float* bk = (const float*)d_in[5];
    const float* Wv = (const float*)d_in[6];
    const float* bv = (const float*)d_in[7];
    const float* Wq = (const float*)d_in[8];
    const float* bq = (const float*)d_in[9];
    const float* Wr = (const float*)d_in[10];
    const float* br = (const float*)d_in[11];
    const float* Wc = (const float*)d_in[12];
    const float* bc = (const float*)d_in[13];
    float* out = (float*)d_out;

    // workspace carve-up (floats); total ~55.9 MB
    float* ws = (float*)d_ws;
    float* WkT   = ws; ws += 64 * 128;
    float* WvT   = ws; ws += 64 * 128;
    float* WqT   = ws; ws += 128 * 128;
    float* WrT   = ws; ws += 128 * 128;
    float* WcT   = ws; ws += 128 * 128;
    float* maskb = ws; ws += B_ * L_;
    float* kproj = ws; ws += (size_t)B_ * L_ * F_;
    float* lsvb  = ws; ws += (size_t)B_ * L_ * F_;
    float* qb    = ws; ws += (size_t)T_ * B_ * V_ * F_;
    float* rb    = ws; ws += (size_t)T_ * B_ * V_ * F_;
    float* rattb = ws; ws += (size_t)T_ * B_ * V_ * F_;

    k_transpose<<<(128 * 64 + 255) / 256, 256, 0, stream>>>(Wk, WkT, 128, 64);
    k_transpose<<<(128 * 64 + 255) / 256, 256, 0, stream>>>(Wv, WvT, 128, 64);
    k_transpose<<<(128 * 128 + 255) / 256, 256, 0, stream>>>(Wq, WqT, 128, 128);
    k_transpose<<<(128 * 128 + 255) / 256, 256, 0, stream>>>(Wr, WrT, 128, 128);
    k_transpose<<<(128 * 128 + 255) / 256, 256, 0, stream>>>(Wc, WcT, 128, 128);
    k_mask<<<(B_ * L_ + 255) / 256, 256, 0, stream>>>(mask, maskb);

    k_lanes<<<(B_ * L_) / 8, 128, 0, stream>>>(lanes, WkT, bk, WvT, bv, kproj, lsvb);
    k_qr<<<(T_ * B_ * V_) / 8, 128, 0, stream>>>(vehicles, initial_pos, WqT, bq, WrT, br, qb, rb);
    k_attn<<<T_ * B_ * H_, 256, 0, stream>>>(kproj, lsvb, maskb, qb, rb, rattb);
    k_out<<<(T_ * B_ * V_) / 8, 128, 0, stream>>>(rattb, WcT, bc, vehicles, initial_pos, out);
}

// Round 2
// 267.727 us; speedup vs baseline: 1.8663x; 1.8663x over previous
//
#include <hip/hip_runtime.h>
#include <hip/hip_bf16.h>
#include <math.h>

// Problem dims
#define T_ 30
#define B_ 32
#define V_ 32
#define F_ 128
#define L_ 256
#define LF_ 64
#define H_ 8
#define DH_ 16
#define HIST_ 10

typedef __attribute__((ext_vector_type(4))) float floatx4;
typedef __attribute__((ext_vector_type(8))) short shortx8;
typedef __attribute__((ext_vector_type(4))) unsigned short ushortx4;

#define MFMA_BF16(a, b, c) __builtin_amdgcn_mfma_f32_16x16x32_bf16(a, b, c, 0, 0, 0)

__device__ inline unsigned short f2bf_rne(float x) {
    unsigned int u = __builtin_bit_cast(unsigned int, x);
    unsigned int r = (u + 0x7fffu + ((u >> 16) & 1u)) >> 16;
    return (unsigned short)r;
}
__device__ inline unsigned short f2bf_trunc(float x) {
    return (unsigned short)(__builtin_bit_cast(unsigned int, x) >> 16);
}

// ---------- generic small transpose ----------
__global__ void k_transpose(const float* __restrict__ in, float* __restrict__ out,
                            int rows, int cols) {
    int idx = blockIdx.x * 256 + threadIdx.x;
    if (idx >= rows * cols) return;
    int r = idx / cols, c = idx % cols;
    out[c * rows + r] = in[idx];
}

// ---------- mask reduction ----------
__global__ void k_mask(const int* __restrict__ m, float* __restrict__ mb) {
    int idx = blockIdx.x * 256 + threadIdx.x;
    if (idx >= B_ * L_) return;
    int any = 0;
#pragma unroll
    for (int h = 0; h < HIST_; ++h) any |= m[h * (B_ * L_) + idx];
    mb[idx] = any ? 1.0f : 0.0f;
}

__device__ inline float logsig(float x) {
    return (x >= 0.f) ? -log1pf(expf(-x)) : x - log1pf(expf(x));
}

// ---------- lane projections ----------
__global__ __launch_bounds__(128) void k_lanes(
    const float* __restrict__ lanes, const float* __restrict__ WkT,
    const float* __restrict__ bk, const float* __restrict__ WvT,
    const float* __restrict__ bv, float* __restrict__ kproj,
    float* __restrict__ lsv) {
    __shared__ float lrow[8][LF_];
    int f = threadIdx.x;
    int row0 = blockIdx.x * 8;
    for (int i = f; i < 8 * LF_; i += 128)
        lrow[i / LF_][i % LF_] = lanes[(size_t)row0 * LF_ + i];
    __syncthreads();
    float ak[8], av[8];
#pragma unroll
    for (int r = 0; r < 8; ++r) { ak[r] = 0.f; av[r] = 0.f; }
    for (int j = 0; j < LF_; ++j) {
        float wk = WkT[j * F_ + f], wv = WvT[j * F_ + f];
#pragma unroll
        for (int r = 0; r < 8; ++r) {
            float lj = lrow[r][j];
            ak[r] += lj * wk;
            av[r] += lj * wv;
        }
    }
    float bkf = bk[f], bvf = bv[f];
#pragma unroll
    for (int r = 0; r < 8; ++r) {
        size_t o = (size_t)(row0 + r) * F_ + f;
        kproj[o] = ak[r] + bkf;
        lsv[o]   = logsig(av[r] + bvf);
    }
}

// ---------- vehicle projections ----------
__global__ __launch_bounds__(128) void k_qr(
    const float* __restrict__ veh, const float* __restrict__ ip,
    const float* __restrict__ WqT, const float* __restrict__ bq,
    const float* __restrict__ WrT, const float* __restrict__ br,
    float* __restrict__ qb, float* __restrict__ rb) {
    __shared__ float vrow[8][F_];
    int f = threadIdx.x;
    int row0 = blockIdx.x * 8;
    for (int i = f; i < 8 * F_; i += 128) {
        size_t g = (size_t)row0 * F_ + i;
        vrow[i / F_][i % F_] = veh[g] + ip[g];
    }
    __syncthreads();
    float aq[8], ar[8];
#pragma unroll
    for (int r = 0; r < 8; ++r) { aq[r] = 0.f; ar[r] = 0.f; }
    for (int j = 0; j < F_; ++j) {
        float wq = WqT[j * F_ + f], wr = WrT[j * F_ + f];
#pragma unroll
        for (int r = 0; r < 8; ++r) {
            float vj = vrow[r][j];
            aq[r] += vj * wq;
            ar[r] += vj * wr;
        }
    }
    float bqf = bq[f], brf = br[f];
#pragma unroll
    for (int r = 0; r < 8; ++r) {
        size_t o = (size_t)(row0 + r) * F_ + f;
        qb[o] = (aq[r] + bqf) * 0.25f;
        rb[o] = ar[r] + brf;
    }
}

// ---------- MFMA attention ----------
// grid = 4 * B_ * H_ blocks; block = 256 threads = 4 waves.
// blockIdx: tc = blk >> 8 (quarter of the 60 query-tiles), bh = blk & 255.
// Computes S^T = K·Q^T per 16-query tile via mfma_f32_16x16x32_bf16 (d padded
// 16->32 with zeros), softmax per query column (lane-local + 2 shfl_xor),
// P^T staged wave-private in LDS (b64 writes / b128 reads), then
// U^T = V^T·P^T via MFMA; epilogue exp(U/sum)*r stored as [T,B,H,V,DH].
__global__ __launch_bounds__(256, 2) void k_attn(
    const float* __restrict__ kproj, const float* __restrict__ lsv,
    const float* __restrict__ maskb, const float* __restrict__ qbuf,
    const float* __restrict__ rbuf, float* __restrict__ ratt) {
    // kS: 256 l-rows x 16 d bf16, row stride 24 ush (48B, 16B-aligned reads)
    __shared__ unsigned short kS[256 * 24];     // 12288 B
    // vT: 16 d-rows x 256 l bf16, row stride 264 ush (528B)
    __shared__ unsigned short vT[16 * 264];     // 8448 B
    // pE: per-wave 16 q-rows x 256 l bf16, row stride 264 ush
    __shared__ unsigned short pE[4 * 16 * 264]; // 33792 B
    __shared__ float mS[256];                   // mask floats

    int tid = threadIdx.x;
    int bh = blockIdx.x & 255;
    int tc = blockIdx.x >> 8;        // 0..3
    int h = bh & 7;
    int b = bh >> 3;

    // ---- stage K (row-major bf16) and V^T (transposed bf16) ----
    const float* kbase = kproj + ((size_t)b * L_) * F_ + h * DH_;
    const float* vbase = lsv   + ((size_t)b * L_) * F_ + h * DH_;
#pragma unroll
    for (int it = 0; it < 4; ++it) {
        int idx = it * 256 + tid;            // 0..1023
        int l = idx >> 2, g = idx & 3;       // g: which float4 of the 16 d's
        floatx4 kv = *(const floatx4*)(kbase + (size_t)l * F_ + g * 4);
        ushortx4 kb;
        kb.x = f2bf_rne(kv.x); kb.y = f2bf_rne(kv.y);
        kb.z = f2bf_rne(kv.z); kb.w = f2bf_rne(kv.w);
        *(ushortx4*)(kS + l * 24 + g * 4) = kb;
        floatx4 vv = *(const floatx4*)(vbase + (size_t)l * F_ + g * 4);
        vT[(g * 4 + 0) * 264 + l] = f2bf_rne(vv.x);
        vT[(g * 4 + 1) * 264 + l] = f2bf_rne(vv.y);
        vT[(g * 4 + 2) * 264 + l] = f2bf_rne(vv.z);
        vT[(g * 4 + 3) * 264 + l] = f2bf_rne(vv.w);
    }
    mS[tid] = maskb[b * L_ + tid];
    __syncthreads();

    int lane = tid & 63, w = tid >> 6;
    int c = lane & 15, quad = lane >> 4;

    // ---- per-lane mask bitmask: bit lt of mreg[reg] = mask[lt*16+quad*4+reg]
    unsigned int mreg[4] = {0u, 0u, 0u, 0u};
#pragma unroll
    for (int lt = 0; lt < 16; ++lt) {
        floatx4 mv = *(const floatx4*)(mS + lt * 16 + quad * 4);
#pragma unroll
        for (int reg = 0; reg < 4; ++reg)
            mreg[reg] |= (mv[reg] > 0.5f ? 1u : 0u) << lt;
    }

    // ---- preload K A-frags (16 l-tiles) and V^T A-frags (8 k-steps) ----
    shortx8 kF[16];
#pragma unroll
    for (int lt = 0; lt < 16; ++lt) {
        shortx8 z = {0, 0, 0, 0, 0, 0, 0, 0};
        kF[lt] = (quad < 2) ? *(const shortx8*)(kS + (lt * 16 + c) * 24 + quad * 8) : z;
    }
    shortx8 vF[8];
#pragma unroll
    for (int kk = 0; kk < 8; ++kk)
        vF[kk] = *(const shortx8*)(vT + c * 264 + kk * 32 + quad * 8);

    unsigned short* pEw = pE + w * (16 * 264);

    // ---- M-loop: 15 query-tiles per block, 4 waves x 4 iters ----
    for (int i = 0; i < 4; ++i) {
        int mtl = i * 4 + w;
        bool act = mtl < 15;
        int mt = tc * 15 + mtl;
        int q0 = mt << 4;
        int t = q0 >> 5, v0 = q0 & 31;
        size_t qrow0 = ((size_t)(t * B_ + b) * V_ + v0 + c) * F_ + h * DH_;
        float sum = 0.f;
        floatx4 cS[16];

        if (act) {
            // Q B-frag: B[k=d][n=query c], d = quad*8+j (quads 2,3 zero)
            shortx8 qF = {0, 0, 0, 0, 0, 0, 0, 0};
            if (quad < 2) {
                floatx4 qa = *(const floatx4*)(qbuf + qrow0 + quad * 8);
                floatx4 qc = *(const floatx4*)(qbuf + qrow0 + quad * 8 + 4);
                qF[0] = (short)f2bf_rne(qa.x); qF[1] = (short)f2bf_rne(qa.y);
                qF[2] = (short)f2bf_rne(qa.z); qF[3] = (short)f2bf_rne(qa.w);
                qF[4] = (short)f2bf_rne(qc.x); qF[5] = (short)f2bf_rne(qc.y);
                qF[6] = (short)f2bf_rne(qc.z); qF[7] = (short)f2bf_rne(qc.w);
            }
            floatx4 z4 = {0.f, 0.f, 0.f, 0.f};
#pragma unroll
            for (int lt = 0; lt < 16; ++lt)
                cS[lt] = MFMA_BF16(kF[lt], qF, z4);   // S^T[l_loc][q]

            // column softmax stats (each lane: fixed query c, 64 l's)
            float mx = -3.0e38f;
#pragma unroll
            for (int lt = 0; lt < 16; ++lt)
                mx = fmaxf(mx, fmaxf(fmaxf(cS[lt][0], cS[lt][1]),
                                     fmaxf(cS[lt][2], cS[lt][3])));
            mx = fmaxf(mx, __shfl_xor(mx, 16));
            mx = fmaxf(mx, __shfl_xor(mx, 32));

#pragma unroll
            for (int lt = 0; lt < 16; ++lt) {
                ushortx4 ep;
#pragma unroll
                for (int reg = 0; reg < 4; ++reg) {
                    float bitf = (float)((mreg[reg] >> lt) & 1u);
                    float e = __expf(cS[lt][reg] - mx) * bitf;
                    sum += e;
                    ep[reg] = f2bf_trunc(e);
                }
                // pE[q=c][l = lt*16 + quad*4 + reg]
                *(ushortx4*)(pEw + c * 264 + lt * 16 + quad * 4) = ep;
            }
            sum += __shfl_xor(sum, 16);
            sum += __shfl_xor(sum, 32);
        }
        __syncthreads();   // order pE writes before reads (correctness hammer)

        if (act) {
            floatx4 cU = {0.f, 0.f, 0.f, 0.f};
#pragma unroll
            for (int kk = 0; kk < 8; ++kk) {
                shortx8 bP = *(const shortx8*)(pEw + c * 264 + kk * 32 + quad * 8);
                cU = MFMA_BF16(vF[kk], bP, cU);       // U^T[d][q]
            }
            float inv = __builtin_amdgcn_rcpf(sum);
            floatx4 rv = *(const floatx4*)(rbuf + qrow0 + quad * 4);
            floatx4 o;
#pragma unroll
            for (int reg = 0; reg < 4; ++reg)
                o[reg] = rv[reg] * __expf(cU[reg] * inv);
            *(floatx4*)(ratt + (((size_t)t * B_ + b) * H_ + h) * (V_ * DH_)
                        + (v0 + c) * DH_ + quad * 4) = o;
        }
        __syncthreads();   // pE reuse fence for next iteration
    }
}

// ---------- combine ----------
__global__ __launch_bounds__(128) void k_out(
    const float* __restrict__ ratt, const float* __restrict__ WcT,
    const float* __restrict__ bc, const float* __restrict__ veh,
    const float* __restrict__ ip, float* __restrict__ out) {
    __shared__ float rr[8][F_];
    int f = threadIdx.x;
    int row0 = blockIdx.x * 8;
    for (int i = f; i < 8 * F_; i += 128)
        rr[i / F_][i % F_] = ratt[(size_t)row0 * F_ + i];
    __syncthreads();
    float acc[8];
#pragma unroll
    for (int r = 0; r < 8; ++r) acc[r] = 0.f;
    for (int j = 0; j < F_; ++j) {
        float wc = WcT[j * F_ + f];
#pragma unroll
        for (int r = 0; r < 8; ++r) acc[r] += rr[r][j] * wc;
    }
    float bcf = bc[f];
#pragma unroll
    for (int r = 0; r < 8; ++r) {
        size_t o = (size_t)(row0 + r) * F_ + f;
        out[o] = acc[r] + bcf + veh[o] - ip[o];
    }
}

extern "C" void kernel_launch(void* const* d_in, const int* in_sizes, int n_in,
                              void* d_out, int out_size, void* d_ws, size_t ws_size,
                              hipStream_t stream) {
    const float* vehicles    = (const float*)d_in[0];
    const float* initial_pos = (const float*)d_in[1];
    const float* lanes       = (const float*)d_in[2];
    const int*   mask        = (const int*)d_in[3];
    const float* Wk = (const float*)d_in[4];
    const float* bk = (const float*)d_in[5];
    const float* Wv = (const float*)d_in[6];
    const float* bv = (const float*)d_in[7];
    const float* Wq = (const float*)d_in[8];
    const float* bq = (const float*)d_in[9];
    const float* Wr = (const float*)d_in[10];
    const float* br = (const float*)d_in[11];
    const float* Wc = (const float*)d_in[12];
    const float* bc = (const float*)d_in[13];
    float* out = (float*)d_out;

    float* ws = (float*)d_ws;
    float* WkT   = ws; ws += 64 * 128;
    float* WvT   = ws; ws += 64 * 128;
    float* WqT   = ws; ws += 128 * 128;
    float* WrT   = ws; ws += 128 * 128;
    float* WcT   = ws; ws += 128 * 128;
    float* maskb = ws; ws += B_ * L_;
    float* kproj = ws; ws += (size_t)B_ * L_ * F_;
    float* lsvb  = ws; ws += (size_t)B_ * L_ * F_;
    float* qb    = ws; ws += (size_t)T_ * B_ * V_ * F_;
    float* rb    = ws; ws += (size_t)T_ * B_ * V_ * F_;
    float* rattb = ws; ws += (size_t)T_ * B_ * V_ * F_;

    k_transpose<<<(128 * 64 + 255) / 256, 256, 0, stream>>>(Wk, WkT, 128, 64);
    k_transpose<<<(128 * 64 + 255) / 256, 256, 0, stream>>>(Wv, WvT, 128, 64);
    k_transpose<<<(128 * 128 + 255) / 256, 256, 0, stream>>>(Wq, WqT, 128, 128);
    k_transpose<<<(128 * 128 + 255) / 256, 256, 0, stream>>>(Wr, WrT, 128, 128);
    k_transpose<<<(128 * 128 + 255) / 256, 256, 0, stream>>>(Wc, WcT, 128, 128);
    k_mask<<<(B_ * L_ + 255) / 256, 256, 0, stream>>>(mask, maskb);

    k_lanes<<<(B_ * L_) / 8, 128, 0, stream>>>(lanes, WkT, bk, WvT, bv, kproj, lsvb);
    k_qr<<<(T_ * B_ * V_) / 8, 128, 0, stream>>>(vehicles, initial_pos, WqT, bq, WrT, br, qb, rb);
    k_attn<<<4 * B_ * H_, 256, 0, stream>>>(kproj, lsvb, maskb, qb, rb, rattb);
    k_out<<<(T_ * B_ * V_) / 8, 128, 0, stream>>>(rattb, WcT, bc, vehicles, initial_pos, out);
}

// Round 3
// 178.000 us; speedup vs baseline: 2.8070x; 1.5041x over previous
//
#include <hip/hip_runtime.h>
#include <hip/hip_bf16.h>
#include <math.h>

// Problem dims
#define T_ 30
#define B_ 32
#define V_ 32
#define F_ 128
#define L_ 256
#define LF_ 64
#define H_ 8
#define DH_ 16
#define HIST_ 10

typedef __attribute__((ext_vector_type(4))) float floatx4;
typedef __attribute__((ext_vector_type(8))) short shortx8;
typedef __attribute__((ext_vector_type(4))) unsigned short ushortx4;

#define MFMA_BF16(a, b, c) __builtin_amdgcn_mfma_f32_16x16x32_bf16(a, b, c, 0, 0, 0)

__device__ inline unsigned short f2bf_rne(float x) {
    unsigned int u = __builtin_bit_cast(unsigned int, x);
    unsigned int r = (u + 0x7fffu + ((u >> 16) & 1u)) >> 16;
    return (unsigned short)r;
}
__device__ inline unsigned short f2bf_trunc(float x) {
    return (unsigned short)(__builtin_bit_cast(unsigned int, x) >> 16);
}
__device__ inline ushortx4 cvt4(floatx4 a) {
    ushortx4 r;
    r.x = f2bf_rne(a.x); r.y = f2bf_rne(a.y);
    r.z = f2bf_rne(a.z); r.w = f2bf_rne(a.w);
    return r;
}

// ---------- mask reduction ----------
__global__ void k_mask(const int* __restrict__ m, float* __restrict__ mb) {
    int idx = blockIdx.x * 256 + threadIdx.x;
    if (idx >= B_ * L_) return;
    int any = 0;
#pragma unroll
    for (int h = 0; h < HIST_; ++h) any |= m[h * (B_ * L_) + idx];
    mb[idx] = any ? 1.0f : 0.0f;
}

// ---------- lane projections (MFMA): kproj/lsv bf16 [B*L][128] ----------
// Block: 256 thr / 4 waves, M-tile 64 (wave w: rows blk*64+16w..+15), K=64.
__global__ __launch_bounds__(256, 2) void k_lanes(
    const float* __restrict__ lanes, const float* __restrict__ Wk,
    const float* __restrict__ bk, const float* __restrict__ Wv,
    const float* __restrict__ bv, unsigned short* __restrict__ kproj,
    unsigned short* __restrict__ lsv) {
    __shared__ unsigned short WkF[8192];  // frag-order: [(nt*2+ks)*64+lane][8]
    __shared__ unsigned short WvF[8192];
    int tid = threadIdx.x;
    for (int g = tid; g < 1024; g += 256) {
        int frag = g >> 6, l = g & 63, cc = l & 15, qq = l >> 4;
        int nt = frag >> 1, ks = frag & 1;
        int n = nt * 16 + cc, k0 = ks * 32 + qq * 8;
        floatx4 a0 = *(const floatx4*)(Wk + n * LF_ + k0);
        floatx4 a1 = *(const floatx4*)(Wk + n * LF_ + k0 + 4);
        *(ushortx4*)(WkF + g * 8) = cvt4(a0);
        *(ushortx4*)(WkF + g * 8 + 4) = cvt4(a1);
        floatx4 b0 = *(const floatx4*)(Wv + n * LF_ + k0);
        floatx4 b1 = *(const floatx4*)(Wv + n * LF_ + k0 + 4);
        *(ushortx4*)(WvF + g * 8) = cvt4(b0);
        *(ushortx4*)(WvF + g * 8 + 4) = cvt4(b1);
    }
    __syncthreads();
    int lane = tid & 63, w = tid >> 6;
    int c = lane & 15, quad = lane >> 4;
    int m0 = blockIdx.x * 64 + w * 16;
    shortx8 aF[2];
#pragma unroll
    for (int ks = 0; ks < 2; ++ks) {
        const float* xp = lanes + (size_t)(m0 + c) * LF_ + ks * 32 + quad * 8;
        floatx4 x0 = *(const floatx4*)(xp);
        floatx4 x1 = *(const floatx4*)(xp + 4);
        ushortx4 lo = cvt4(x0), hi = cvt4(x1);
        shortx8 af;
        af[0]=(short)lo.x; af[1]=(short)lo.y; af[2]=(short)lo.z; af[3]=(short)lo.w;
        af[4]=(short)hi.x; af[5]=(short)hi.y; af[6]=(short)hi.z; af[7]=(short)hi.w;
        aF[ks] = af;
    }
#pragma unroll
    for (int nt = 0; nt < 8; ++nt) {
        floatx4 acck = {0.f, 0.f, 0.f, 0.f}, accv = {0.f, 0.f, 0.f, 0.f};
#pragma unroll
        for (int ks = 0; ks < 2; ++ks) {
            shortx8 bkf = *(const shortx8*)(WkF + ((nt * 2 + ks) * 64 + lane) * 8);
            shortx8 bvf = *(const shortx8*)(WvF + ((nt * 2 + ks) * 64 + lane) * 8);
            acck = MFMA_BF16(aF[ks], bkf, acck);
            accv = MFMA_BF16(aF[ks], bvf, accv);
        }
        int n = nt * 16 + c;
        float bkn = bk[n], bvn = bv[n];
#pragma unroll
        for (int reg = 0; reg < 4; ++reg) {
            size_t row = m0 + quad * 4 + reg;
            kproj[row * F_ + n] = f2bf_rne(acck[reg] + bkn);
            float xv = accv[reg] + bvn;
            float ls = fminf(xv, 0.f) - log1pf(__expf(-fabsf(xv)));
            lsv[row * F_ + n] = f2bf_rne(ls);
        }
    }
}

// ---------- vehicle projections (MFMA): qb bf16, rb fp32 ----------
__global__ __launch_bounds__(256, 2) void k_qr(
    const float* __restrict__ veh, const float* __restrict__ ip,
    const float* __restrict__ Wq, const float* __restrict__ bq,
    const float* __restrict__ Wr, const float* __restrict__ br,
    unsigned short* __restrict__ qb, float* __restrict__ rb) {
    __shared__ unsigned short WqF[16384];  // [(nt*4+ks)*64+lane][8]
    __shared__ unsigned short WrF[16384];
    int tid = threadIdx.x;
    for (int g = tid; g < 2048; g += 256) {
        int frag = g >> 6, l = g & 63, cc = l & 15, qq = l >> 4;
        int nt = frag >> 2, ks = frag & 3;
        int n = nt * 16 + cc, k0 = ks * 32 + qq * 8;
        floatx4 a0 = *(const floatx4*)(Wq + n * F_ + k0);
        floatx4 a1 = *(const floatx4*)(Wq + n * F_ + k0 + 4);
        *(ushortx4*)(WqF + g * 8) = cvt4(a0);
        *(ushortx4*)(WqF + g * 8 + 4) = cvt4(a1);
        floatx4 b0 = *(const floatx4*)(Wr + n * F_ + k0);
        floatx4 b1 = *(const floatx4*)(Wr + n * F_ + k0 + 4);
        *(ushortx4*)(WrF + g * 8) = cvt4(b0);
        *(ushortx4*)(WrF + g * 8 + 4) = cvt4(b1);
    }
    __syncthreads();
    int lane = tid & 63, w = tid >> 6;
    int c = lane & 15, quad = lane >> 4;
    int m0 = blockIdx.x * 64 + w * 16;
    shortx8 aF[4];
#pragma unroll
    for (int ks = 0; ks < 4; ++ks) {
        size_t off = (size_t)(m0 + c) * F_ + ks * 32 + quad * 8;
        floatx4 v0 = *(const floatx4*)(veh + off);
        floatx4 v1 = *(const floatx4*)(veh + off + 4);
        floatx4 i0 = *(const floatx4*)(ip + off);
        floatx4 i1 = *(const floatx4*)(ip + off + 4);
        ushortx4 lo = cvt4(v0 + i0), hi = cvt4(v1 + i1);
        shortx8 af;
        af[0]=(short)lo.x; af[1]=(short)lo.y; af[2]=(short)lo.z; af[3]=(short)lo.w;
        af[4]=(short)hi.x; af[5]=(short)hi.y; af[6]=(short)hi.z; af[7]=(short)hi.w;
        aF[ks] = af;
    }
#pragma unroll
    for (int nt = 0; nt < 8; ++nt) {
        floatx4 accq = {0.f, 0.f, 0.f, 0.f}, accr = {0.f, 0.f, 0.f, 0.f};
#pragma unroll
        for (int ks = 0; ks < 4; ++ks) {
            shortx8 bqf = *(const shortx8*)(WqF + ((nt * 4 + ks) * 64 + lane) * 8);
            shortx8 brf = *(const shortx8*)(WrF + ((nt * 4 + ks) * 64 + lane) * 8);
            accq = MFMA_BF16(aF[ks], bqf, accq);
            accr = MFMA_BF16(aF[ks], brf, accr);
        }
        int n = nt * 16 + c;
        float bqn = bq[n], brn = br[n];
#pragma unroll
        for (int reg = 0; reg < 4; ++reg) {
            size_t row = m0 + quad * 4 + reg;
            qb[row * F_ + n] = f2bf_rne((accq[reg] + bqn) * 0.25f);
            rb[row * F_ + n] = accr[reg] + brn;
        }
    }
}

// ---------- MFMA attention (interfaces now bf16) ----------
__global__ __launch_bounds__(256, 2) void k_attn(
    const unsigned short* __restrict__ kproj, const unsigned short* __restrict__ lsv,
    const float* __restrict__ maskb, const unsigned short* __restrict__ qbuf,
    const float* __restrict__ rbuf, unsigned short* __restrict__ ratt) {
    __shared__ unsigned short kS[256 * 24];     // [l][16d], stride 24
    __shared__ unsigned short vT[16 * 264];     // [d][l], stride 264
    __shared__ unsigned short pE[4 * 16 * 264]; // per-wave [q][l]
    __shared__ float mS[256];

    int tid = threadIdx.x;
    int bh = blockIdx.x & 255;
    int tc = blockIdx.x >> 8;
    int h = bh & 7;
    int b = bh >> 3;

    const unsigned short* kbase = kproj + ((size_t)b * L_) * F_ + h * DH_;
    const unsigned short* vbase = lsv   + ((size_t)b * L_) * F_ + h * DH_;
#pragma unroll
    for (int it = 0; it < 2; ++it) {
        int id = it * 256 + tid;        // 0..511
        int l = id >> 1, half = id & 1;
        shortx8 kv = *(const shortx8*)(kbase + (size_t)l * F_ + half * 8);
        *(shortx8*)(kS + l * 24 + half * 8) = kv;
        shortx8 vv = *(const shortx8*)(vbase + (size_t)l * F_ + half * 8);
#pragma unroll
        for (int j = 0; j < 8; ++j)
            vT[(half * 8 + j) * 264 + l] = (unsigned short)vv[j];
    }
    mS[tid] = maskb[b * L_ + tid];
    __syncthreads();

    int lane = tid & 63, w = tid >> 6;
    int c = lane & 15, quad = lane >> 4;

    unsigned int mreg[4] = {0u, 0u, 0u, 0u};
#pragma unroll
    for (int lt = 0; lt < 16; ++lt) {
        floatx4 mv = *(const floatx4*)(mS + lt * 16 + quad * 4);
#pragma unroll
        for (int reg = 0; reg < 4; ++reg)
            mreg[reg] |= (mv[reg] > 0.5f ? 1u : 0u) << lt;
    }

    shortx8 kF[16];
#pragma unroll
    for (int lt = 0; lt < 16; ++lt) {
        shortx8 z = {0, 0, 0, 0, 0, 0, 0, 0};
        kF[lt] = (quad < 2) ? *(const shortx8*)(kS + (lt * 16 + c) * 24 + quad * 8) : z;
    }
    shortx8 vF[8];
#pragma unroll
    for (int kk = 0; kk < 8; ++kk)
        vF[kk] = *(const shortx8*)(vT + c * 264 + kk * 32 + quad * 8);

    unsigned short* pEw = pE + w * (16 * 264);

    for (int i = 0; i < 4; ++i) {
        int mtl = i * 4 + w;
        bool act = mtl < 15;
        int mt = tc * 15 + mtl;
        int q0 = mt << 4;
        int t = q0 >> 5, v0 = q0 & 31;
        size_t qrow0 = ((size_t)(t * B_ + b) * V_ + v0 + c) * F_ + h * DH_;
        float sum = 0.f;
        floatx4 cS[16];

        if (act) {
            shortx8 qF = {0, 0, 0, 0, 0, 0, 0, 0};
            if (quad < 2) qF = *(const shortx8*)(qbuf + qrow0 + quad * 8);
            floatx4 z4 = {0.f, 0.f, 0.f, 0.f};
#pragma unroll
            for (int lt = 0; lt < 16; ++lt)
                cS[lt] = MFMA_BF16(kF[lt], qF, z4);

            float mx = -3.0e38f;
#pragma unroll
            for (int lt = 0; lt < 16; ++lt)
                mx = fmaxf(mx, fmaxf(fmaxf(cS[lt][0], cS[lt][1]),
                                     fmaxf(cS[lt][2], cS[lt][3])));
            mx = fmaxf(mx, __shfl_xor(mx, 16));
            mx = fmaxf(mx, __shfl_xor(mx, 32));

#pragma unroll
            for (int lt = 0; lt < 16; ++lt) {
                ushortx4 ep;
#pragma unroll
                for (int reg = 0; reg < 4; ++reg) {
                    float bitf = (float)((mreg[reg] >> lt) & 1u);
                    float e = __expf(cS[lt][reg] - mx) * bitf;
                    sum += e;
                    ep[reg] = f2bf_trunc(e);
                }
                *(ushortx4*)(pEw + c * 264 + lt * 16 + quad * 4) = ep;
            }
            sum += __shfl_xor(sum, 16);
            sum += __shfl_xor(sum, 32);
        }
        __syncthreads();

        if (act) {
            floatx4 cU = {0.f, 0.f, 0.f, 0.f};
#pragma unroll
            for (int kk = 0; kk < 8; ++kk) {
                shortx8 bP = *(const shortx8*)(pEw + c * 264 + kk * 32 + quad * 8);
                cU = MFMA_BF16(vF[kk], bP, cU);
            }
            float inv = __builtin_amdgcn_rcpf(sum);
            floatx4 rv = *(const floatx4*)(rbuf + qrow0 + quad * 4);
            ushortx4 ob;
#pragma unroll
            for (int reg = 0; reg < 4; ++reg)
                ob[reg] = f2bf_rne(rv[reg] * __expf(cU[reg] * inv));
            *(ushortx4*)(ratt + (((size_t)t * B_ + b) * H_ + h) * (V_ * DH_)
                        + (v0 + c) * DH_ + quad * 4) = ob;
        }
        __syncthreads();
    }
}

// ---------- combine (MFMA): out = ratt@Wc^T + bc + veh - ip ----------
__global__ __launch_bounds__(256, 2) void k_out(
    const unsigned short* __restrict__ ratt, const float* __restrict__ Wc,
    const float* __restrict__ bc, const float* __restrict__ veh,
    const float* __restrict__ ip, float* __restrict__ out) {
    __shared__ unsigned short WcF[16384];
    int tid = threadIdx.x;
    for (int g = tid; g < 2048; g += 256) {
        int frag = g >> 6, l = g & 63, cc = l & 15, qq = l >> 4;
        int nt = frag >> 2, ks = frag & 3;
        int n = nt * 16 + cc, k0 = ks * 32 + qq * 8;
        floatx4 a0 = *(const floatx4*)(Wc + n * F_ + k0);
        floatx4 a1 = *(const floatx4*)(Wc + n * F_ + k0 + 4);
        *(ushortx4*)(WcF + g * 8) = cvt4(a0);
        *(ushortx4*)(WcF + g * 8 + 4) = cvt4(a1);
    }
    __syncthreads();
    int lane = tid & 63, w = tid >> 6;
    int c = lane & 15, quad = lane >> 4;
    int m0 = blockIdx.x * 64 + w * 16;
    shortx8 aF[4];
#pragma unroll
    for (int ks = 0; ks < 4; ++ks)
        aF[ks] = *(const shortx8*)(ratt + (size_t)(m0 + c) * F_ + ks * 32 + quad * 8);
#pragma unroll
    for (int np = 0; np < 4; ++np) {
        int nt0 = np * 2, nt1 = np * 2 + 1;
        floatx4 acc0 = {0.f, 0.f, 0.f, 0.f}, acc1 = {0.f, 0.f, 0.f, 0.f};
#pragma unroll
        for (int ks = 0; ks < 4; ++ks) {
            shortx8 b0 = *(const shortx8*)(WcF + ((nt0 * 4 + ks) * 64 + lane) * 8);
            shortx8 b1 = *(const shortx8*)(WcF + ((nt1 * 4 + ks) * 64 + lane) * 8);
            acc0 = MFMA_BF16(aF[ks], b0, acc0);
            acc1 = MFMA_BF16(aF[ks], b1, acc1);
        }
        int n0 = nt0 * 16 + c, n1 = nt1 * 16 + c;
        float bc0 = bc[n0], bc1 = bc[n1];
#pragma unroll
        for (int reg = 0; reg < 4; ++reg) {
            size_t row = m0 + quad * 4 + reg;
            size_t o0 = row * F_ + n0, o1 = row * F_ + n1;
            out[o0] = acc0[reg] + bc0 + veh[o0] - ip[o0];
            out[o1] = acc1[reg] + bc1 + veh[o1] - ip[o1];
        }
    }
}

extern "C" void kernel_launch(void* const* d_in, const int* in_sizes, int n_in,
                              void* d_out, int out_size, void* d_ws, size_t ws_size,
                              hipStream_t stream) {
    const float* vehicles    = (const float*)d_in[0];
    const float* initial_pos = (const float*)d_in[1];
    const float* lanes       = (const float*)d_in[2];
    const int*   mask        = (const int*)d_in[3];
    const float* Wk = (const float*)d_in[4];
    const float* bk = (const float*)d_in[5];
    const float* Wv = (const float*)d_in[6];
    const float* bv = (const float*)d_in[7];
    const float* Wq = (const float*)d_in[8];
    const float* bq = (const float*)d_in[9];
    const float* Wr = (const float*)d_in[10];
    const float* br = (const float*)d_in[11];
    const float* Wc = (const float*)d_in[12];
    const float* bc = (const float*)d_in[13];
    float* out = (float*)d_out;

    // workspace carve-up (byte-based, 256B-aligned chunks)
    char* p = (char*)d_ws;
    float* maskb = (float*)p;          p += ((B_ * L_ * 4 + 255) / 256) * 256;
    unsigned short* kproj = (unsigned short*)p; p += ((size_t)B_ * L_ * F_ * 2 + 255) / 256 * 256;
    unsigned short* lsvb  = (unsigned short*)p; p += ((size_t)B_ * L_ * F_ * 2 + 255) / 256 * 256;
    unsigned short* qb    = (unsigned short*)p; p += ((size_t)T_ * B_ * V_ * F_ * 2 + 255) / 256 * 256;
    float* rb             = (float*)p;          p += ((size_t)T_ * B_ * V_ * F_ * 4 + 255) / 256 * 256;
    unsigned short* rattb = (unsigned short*)p; p += ((size_t)T_ * B_ * V_ * F_ * 2 + 255) / 256 * 256;

    k_mask<<<(B_ * L_ + 255) / 256, 256, 0, stream>>>(mask, maskb);
    k_lanes<<<(B_ * L_) / 64, 256, 0, stream>>>(lanes, Wk, bk, Wv, bv, kproj, lsvb);
    k_qr<<<(T_ * B_ * V_) / 64, 256, 0, stream>>>(vehicles, initial_pos, Wq, bq, Wr, br, qb, rb);
    k_attn<<<4 * B_ * H_, 256, 0, stream>>>(kproj, lsvb, maskb, qb, rb, rattb);
    k_out<<<(T_ * B_ * V_) / 64, 256, 0, stream>>>(rattb, Wc, bc, vehicles, initial_pos, out);
}

// Round 4
// 168.301 us; speedup vs baseline: 2.9688x; 1.0576x over previous
//
#include <hip/hip_runtime.h>
#include <hip/hip_bf16.h>
#include <math.h>

// Problem dims
#define T_ 30
#define B_ 32
#define V_ 32
#define F_ 128
#define L_ 256
#define LF_ 64
#define H_ 8
#define DH_ 16
#define HIST_ 10

typedef __attribute__((ext_vector_type(4))) float floatx4;
typedef __attribute__((ext_vector_type(8))) short shortx8;
typedef __attribute__((ext_vector_type(4))) unsigned short ushortx4;

#define MFMA_BF16(a, b, c) __builtin_amdgcn_mfma_f32_16x16x32_bf16(a, b, c, 0, 0, 0)

__device__ inline unsigned short f2bf_rne(float x) {
    unsigned int u = __builtin_bit_cast(unsigned int, x);
    unsigned int r = (u + 0x7fffu + ((u >> 16) & 1u)) >> 16;
    return (unsigned short)r;
}
__device__ inline unsigned short f2bf_trunc(float x) {
    return (unsigned short)(__builtin_bit_cast(unsigned int, x) >> 16);
}
__device__ inline float bf2f(unsigned short u) {
    return __builtin_bit_cast(float, (unsigned int)u << 16);
}
__device__ inline ushortx4 cvt4(floatx4 a) {
    ushortx4 r;
    r.x = f2bf_rne(a.x); r.y = f2bf_rne(a.y);
    r.z = f2bf_rne(a.z); r.w = f2bf_rne(a.w);
    return r;
}

// ---------- lane projections (MFMA) + mask + pre-masked transposed V ----------
// kproj bf16 [B*L][128]; lsvT bf16 [B][128][256] (pre-masked); maskb fp32 [B*L]
__global__ __launch_bounds__(256, 2) void k_lanes(
    const float* __restrict__ lanes, const int* __restrict__ mask,
    const float* __restrict__ Wk, const float* __restrict__ bk,
    const float* __restrict__ Wv, const float* __restrict__ bv,
    unsigned short* __restrict__ kproj, unsigned short* __restrict__ lsvT,
    float* __restrict__ maskb) {
    __shared__ unsigned short WkF[8192];  // frag-order: [(nt*2+ks)*64+lane][8]
    __shared__ unsigned short WvF[8192];
    __shared__ float mloc[64];
    int tid = threadIdx.x;
    int m0 = blockIdx.x * 64;
    int b = m0 >> 8;
    // mask any-reduce for this block's 64 rows
    if (tid < 64) {
        int row = m0 + tid;
        int any = 0;
#pragma unroll
        for (int hh = 0; hh < HIST_; ++hh) any |= mask[hh * (B_ * L_) + row];
        float fm = any ? 1.0f : 0.0f;
        maskb[row] = fm;
        mloc[tid] = fm;
    }
    for (int g = tid; g < 1024; g += 256) {
        int frag = g >> 6, l = g & 63, cc = l & 15, qq = l >> 4;
        int nt = frag >> 1, ks = frag & 1;
        int n = nt * 16 + cc, k0 = ks * 32 + qq * 8;
        floatx4 a0 = *(const floatx4*)(Wk + n * LF_ + k0);
        floatx4 a1 = *(const floatx4*)(Wk + n * LF_ + k0 + 4);
        *(ushortx4*)(WkF + g * 8) = cvt4(a0);
        *(ushortx4*)(WkF + g * 8 + 4) = cvt4(a1);
        floatx4 b0 = *(const floatx4*)(Wv + n * LF_ + k0);
        floatx4 b1 = *(const floatx4*)(Wv + n * LF_ + k0 + 4);
        *(ushortx4*)(WvF + g * 8) = cvt4(b0);
        *(ushortx4*)(WvF + g * 8 + 4) = cvt4(b1);
    }
    __syncthreads();
    int lane = tid & 63, w = tid >> 6;
    int c = lane & 15, quad = lane >> 4;
    int mw = m0 + w * 16;
    shortx8 aF[2];
#pragma unroll
    for (int ks = 0; ks < 2; ++ks) {
        const float* xp = lanes + (size_t)(mw + c) * LF_ + ks * 32 + quad * 8;
        floatx4 x0 = *(const floatx4*)(xp);
        floatx4 x1 = *(const floatx4*)(xp + 4);
        ushortx4 lo = cvt4(x0), hi = cvt4(x1);
        shortx8 af;
        af[0]=(short)lo.x; af[1]=(short)lo.y; af[2]=(short)lo.z; af[3]=(short)lo.w;
        af[4]=(short)hi.x; af[5]=(short)hi.y; af[6]=(short)hi.z; af[7]=(short)hi.w;
        aF[ks] = af;
    }
    floatx4 mk = *(const floatx4*)(mloc + w * 16 + quad * 4);
    int lbase = (mw & 255) + quad * 4;
#pragma unroll
    for (int nt = 0; nt < 8; ++nt) {
        floatx4 acck = {0.f, 0.f, 0.f, 0.f}, accv = {0.f, 0.f, 0.f, 0.f};
#pragma unroll
        for (int ks = 0; ks < 2; ++ks) {
            shortx8 bkf = *(const shortx8*)(WkF + ((nt * 2 + ks) * 64 + lane) * 8);
            shortx8 bvf = *(const shortx8*)(WvF + ((nt * 2 + ks) * 64 + lane) * 8);
            acck = MFMA_BF16(aF[ks], bkf, acck);
            accv = MFMA_BF16(aF[ks], bvf, accv);
        }
        int n = nt * 16 + c;
        float bkn = bk[n], bvn = bv[n];
        ushortx4 vout;
#pragma unroll
        for (int reg = 0; reg < 4; ++reg) {
            size_t row = mw + quad * 4 + reg;
            kproj[row * F_ + n] = f2bf_rne(acck[reg] + bkn);
            float xv = accv[reg] + bvn;
            float ls = fminf(xv, 0.f) - log1pf(__expf(-fabsf(xv)));
            vout[reg] = (mk[reg] > 0.5f) ? f2bf_rne(ls) : (unsigned short)0;
        }
        *(ushortx4*)(lsvT + ((size_t)b * F_ + n) * L_ + lbase) = vout;
    }
}

// ---------- vehicle projections (MFMA): qb bf16 (0.25*log2e folded), rb bf16
__global__ __launch_bounds__(256, 2) void k_qr(
    const float* __restrict__ veh, const float* __restrict__ ip,
    const float* __restrict__ Wq, const float* __restrict__ bq,
    const float* __restrict__ Wr, const float* __restrict__ br,
    unsigned short* __restrict__ qb, unsigned short* __restrict__ rb) {
    __shared__ unsigned short WqF[16384];  // [(nt*4+ks)*64+lane][8]
    __shared__ unsigned short WrF[16384];
    int tid = threadIdx.x;
    for (int g = tid; g < 2048; g += 256) {
        int frag = g >> 6, l = g & 63, cc = l & 15, qq = l >> 4;
        int nt = frag >> 2, ks = frag & 3;
        int n = nt * 16 + cc, k0 = ks * 32 + qq * 8;
        floatx4 a0 = *(const floatx4*)(Wq + n * F_ + k0);
        floatx4 a1 = *(const floatx4*)(Wq + n * F_ + k0 + 4);
        *(ushortx4*)(WqF + g * 8) = cvt4(a0);
        *(ushortx4*)(WqF + g * 8 + 4) = cvt4(a1);
        floatx4 b0 = *(const floatx4*)(Wr + n * F_ + k0);
        floatx4 b1 = *(const floatx4*)(Wr + n * F_ + k0 + 4);
        *(ushortx4*)(WrF + g * 8) = cvt4(b0);
        *(ushortx4*)(WrF + g * 8 + 4) = cvt4(b1);
    }
    __syncthreads();
    int lane = tid & 63, w = tid >> 6;
    int c = lane & 15, quad = lane >> 4;
    int m0 = blockIdx.x * 64 + w * 16;
    shortx8 aF[4];
#pragma unroll
    for (int ks = 0; ks < 4; ++ks) {
        size_t off = (size_t)(m0 + c) * F_ + ks * 32 + quad * 8;
        floatx4 v0 = *(const floatx4*)(veh + off);
        floatx4 v1 = *(const floatx4*)(veh + off + 4);
        floatx4 i0 = *(const floatx4*)(ip + off);
        floatx4 i1 = *(const floatx4*)(ip + off + 4);
        ushortx4 lo = cvt4(v0 + i0), hi = cvt4(v1 + i1);
        shortx8 af;
        af[0]=(short)lo.x; af[1]=(short)lo.y; af[2]=(short)lo.z; af[3]=(short)lo.w;
        af[4]=(short)hi.x; af[5]=(short)hi.y; af[6]=(short)hi.z; af[7]=(short)hi.w;
        aF[ks] = af;
    }
    const float QSCALE = 0.25f * 1.4426950408889634f;  // 1/sqrt(DH) * log2(e)
#pragma unroll
    for (int nt = 0; nt < 8; ++nt) {
        floatx4 accq = {0.f, 0.f, 0.f, 0.f}, accr = {0.f, 0.f, 0.f, 0.f};
#pragma unroll
        for (int ks = 0; ks < 4; ++ks) {
            shortx8 bqf = *(const shortx8*)(WqF + ((nt * 4 + ks) * 64 + lane) * 8);
            shortx8 brf = *(const shortx8*)(WrF + ((nt * 4 + ks) * 64 + lane) * 8);
            accq = MFMA_BF16(aF[ks], bqf, accq);
            accr = MFMA_BF16(aF[ks], brf, accr);
        }
        int n = nt * 16 + c;
        float bqn = bq[n], brn = br[n];
#pragma unroll
        for (int reg = 0; reg < 4; ++reg) {
            size_t row = m0 + quad * 4 + reg;
            qb[row * F_ + n] = f2bf_rne((accq[reg] + bqn) * QSCALE);
            rb[row * F_ + n] = f2bf_rne(accr[reg] + brn);
        }
    }
}

// ---------- MFMA attention ----------
// S in exp2 domain (log2e folded into q); no max-subtract (scores bounded);
// V pre-masked in lsvT; denominator via second MFMA with mask A-fragment;
// pE is wave-private (LDS in-order per wave -> no per-tile barriers).
__global__ __launch_bounds__(256, 2) void k_attn(
    const unsigned short* __restrict__ kproj, const unsigned short* __restrict__ lsvT,
    const float* __restrict__ maskb, const unsigned short* __restrict__ qbuf,
    const unsigned short* __restrict__ rbuf, unsigned short* __restrict__ ratt) {
    __shared__ unsigned short kS[256 * 24];     // [l][16d], stride 24
    __shared__ unsigned short vT[16 * 264];     // [d][l], stride 264
    __shared__ unsigned short pE[4 * 16 * 264]; // per-wave [q][l]

    int tid = threadIdx.x;
    int bh = blockIdx.x & 255;
    int tc = blockIdx.x >> 8;
    int h = bh & 7;
    int b = bh >> 3;

    // stage K rows (vectorized)
    const unsigned short* kbase = kproj + ((size_t)b * L_) * F_ + h * DH_;
#pragma unroll
    for (int it = 0; it < 2; ++it) {
        int id = it * 256 + tid;
        int l = id >> 1, half = id & 1;
        shortx8 kv = *(const shortx8*)(kbase + (size_t)l * F_ + half * 8);
        *(shortx8*)(kS + l * 24 + half * 8) = kv;
    }
    // stage V^T from pre-transposed global (coalesced, b128 LDS writes)
    {
        int d = tid >> 4, c16 = tid & 15;
        const unsigned short* vrow = lsvT + ((size_t)b * F_ + h * DH_ + d) * L_ + c16 * 16;
        shortx8 v0 = *(const shortx8*)(vrow);
        shortx8 v1 = *(const shortx8*)(vrow + 8);
        *(shortx8*)(vT + d * 264 + c16 * 16) = v0;
        *(shortx8*)(vT + d * 264 + c16 * 16 + 8) = v1;
    }
    __syncthreads();

    int lane = tid & 63, w = tid >> 6;
    int c = lane & 15, quad = lane >> 4;

    shortx8 kF[16];
#pragma unroll
    for (int lt = 0; lt < 16; ++lt) {
        shortx8 z = {0, 0, 0, 0, 0, 0, 0, 0};
        kF[lt] = (quad < 2) ? *(const shortx8*)(kS + (lt * 16 + c) * 24 + quad * 8) : z;
    }
    shortx8 vF[8];
#pragma unroll
    for (int kk = 0; kk < 8; ++kk)
        vF[kk] = *(const shortx8*)(vT + c * 264 + kk * 32 + quad * 8);
    // mask A-fragment: A[m][k=l] = mask[kk*32 + quad*8 + j] (m-independent)
    shortx8 mF[8];
#pragma unroll
    for (int kk = 0; kk < 8; ++kk) {
        const float* mp = maskb + b * L_ + kk * 32 + quad * 8;
        floatx4 ma = *(const floatx4*)(mp);
        floatx4 mb2 = *(const floatx4*)(mp + 4);
        shortx8 mf;
        mf[0]=(short)f2bf_trunc(ma.x); mf[1]=(short)f2bf_trunc(ma.y);
        mf[2]=(short)f2bf_trunc(ma.z); mf[3]=(short)f2bf_trunc(ma.w);
        mf[4]=(short)f2bf_trunc(mb2.x); mf[5]=(short)f2bf_trunc(mb2.y);
        mf[6]=(short)f2bf_trunc(mb2.z); mf[7]=(short)f2bf_trunc(mb2.w);
        mF[kk] = mf;
    }

    unsigned short* pEw = pE + w * (16 * 264);
    floatx4 z4 = {0.f, 0.f, 0.f, 0.f};

    for (int mtl = w; mtl < 15; mtl += 4) {
        int mt = tc * 15 + mtl;
        int q0 = mt << 4;
        int t = q0 >> 5, v0 = q0 & 31;
        size_t qrow0 = ((size_t)(t * B_ + b) * V_ + v0 + c) * F_ + h * DH_;

        shortx8 qF = {0, 0, 0, 0, 0, 0, 0, 0};
        if (quad < 2) qF = *(const shortx8*)(qbuf + qrow0 + quad * 8);

        // S-tile MFMA + exp2 + pack to wave-private LDS
#pragma unroll
        for (int lt = 0; lt < 16; ++lt) {
            floatx4 s = MFMA_BF16(kF[lt], qF, z4);  // S^T[l][q], exp2 domain
            ushortx4 ep;
#pragma unroll
            for (int reg = 0; reg < 4; ++reg)
                ep[reg] = f2bf_trunc(__builtin_amdgcn_exp2f(s[reg]));
            *(ushortx4*)(pEw + c * 264 + lt * 16 + quad * 4) = ep;
        }

        // U^T = V^T(masked)·P^T ; denom = mask·P^T (rows replicated)
        floatx4 cU = z4, cN = z4;
#pragma unroll
        for (int kk = 0; kk < 8; ++kk) {
            shortx8 bP = *(const shortx8*)(pEw + c * 264 + kk * 32 + quad * 8);
            cU = MFMA_BF16(vF[kk], bP, cU);
            cN = MFMA_BF16(mF[kk], bP, cN);
        }
        float inv2 = __builtin_amdgcn_rcpf(cN[0]) * 1.4426950408889634f;
        ushortx4 rv = *(const ushortx4*)(rbuf + qrow0 + quad * 4);
        ushortx4 ob;
#pragma unroll
        for (int reg = 0; reg < 4; ++reg) {
            float att = __builtin_amdgcn_exp2f(cU[reg] * inv2);  // e^(U/sum)
            ob[reg] = f2bf_rne(bf2f(rv[reg]) * att);
        }
        *(ushortx4*)(ratt + (((size_t)t * B_ + b) * H_ + h) * (V_ * DH_)
                    + (v0 + c) * DH_ + quad * 4) = ob;
    }
}

// ---------- combine (MFMA): out = ratt@Wc^T + bc + veh - ip ----------
__global__ __launch_bounds__(256, 2) void k_out(
    const unsigned short* __restrict__ ratt, const float* __restrict__ Wc,
    const float* __restrict__ bc, const float* __restrict__ veh,
    const float* __restrict__ ip, float* __restrict__ out) {
    __shared__ unsigned short WcF[16384];
    int tid = threadIdx.x;
    for (int g = tid; g < 2048; g += 256) {
        int frag = g >> 6, l = g & 63, cc = l & 15, qq = l >> 4;
        int nt = frag >> 2, ks = frag & 3;
        int n = nt * 16 + cc, k0 = ks * 32 + qq * 8;
        floatx4 a0 = *(const floatx4*)(Wc + n * F_ + k0);
        floatx4 a1 = *(const floatx4*)(Wc + n * F_ + k0 + 4);
        *(ushortx4*)(WcF + g * 8) = cvt4(a0);
        *(ushortx4*)(WcF + g * 8 + 4) = cvt4(a1);
    }
    __syncthreads();
    int lane = tid & 63, w = tid >> 6;
    int c = lane & 15, quad = lane >> 4;
    int m0 = blockIdx.x * 64 + w * 16;
    shortx8 aF[4];
#pragma unroll
    for (int ks = 0; ks < 4; ++ks)
        aF[ks] = *(const shortx8*)(ratt + (size_t)(m0 + c) * F_ + ks * 32 + quad * 8);
#pragma unroll
    for (int np = 0; np < 4; ++np) {
        int nt0 = np * 2, nt1 = np * 2 + 1;
        floatx4 acc0 = {0.f, 0.f, 0.f, 0.f}, acc1 = {0.f, 0.f, 0.f, 0.f};
#pragma unroll
        for (int ks = 0; ks < 4; ++ks) {
            shortx8 b0 = *(const shortx8*)(WcF + ((nt0 * 4 + ks) * 64 + lane) * 8);
            shortx8 b1 = *(const shortx8*)(WcF + ((nt1 * 4 + ks) * 64 + lane) * 8);
            acc0 = MFMA_BF16(aF[ks], b0, acc0);
            acc1 = MFMA_BF16(aF[ks], b1, acc1);
        }
        int n0 = nt0 * 16 + c, n1 = nt1 * 16 + c;
        float bc0 = bc[n0], bc1 = bc[n1];
#pragma unroll
        for (int reg = 0; reg < 4; ++reg) {
            size_t row = m0 + quad * 4 + reg;
            size_t o0 = row * F_ + n0, o1 = row * F_ + n1;
            out[o0] = acc0[reg] + bc0 + veh[o0] - ip[o0];
            out[o1] = acc1[reg] + bc1 + veh[o1] - ip[o1];
        }
    }
}

extern "C" void kernel_launch(void* const* d_in, const int* in_sizes, int n_in,
                              void* d_out, int out_size, void* d_ws, size_t ws_size,
                              hipStream_t stream) {
    const float* vehicles    = (const float*)d_in[0];
    const float* initial_pos = (const float*)d_in[1];
    const float* lanes       = (const float*)d_in[2];
    const int*   mask        = (const int*)d_in[3];
    const float* Wk = (const float*)d_in[4];
    const float* bk = (const float*)d_in[5];
    const float* Wv = (const float*)d_in[6];
    const float* bv = (const float*)d_in[7];
    const float* Wq = (const float*)d_in[8];
    const float* bq = (const float*)d_in[9];
    const float* Wr = (const float*)d_in[10];
    const float* br = (const float*)d_in[11];
    const float* Wc = (const float*)d_in[12];
    const float* bc = (const float*)d_in[13];
    float* out = (float*)d_out;

    char* p = (char*)d_ws;
    float* maskb = (float*)p;                   p += ((B_ * L_ * 4 + 255) / 256) * 256;
    unsigned short* kproj = (unsigned short*)p; p += ((size_t)B_ * L_ * F_ * 2 + 255) / 256 * 256;
    unsigned short* lsvT  = (unsigned short*)p; p += ((size_t)B_ * F_ * L_ * 2 + 255) / 256 * 256;
    unsigned short* qb    = (unsigned short*)p; p += ((size_t)T_ * B_ * V_ * F_ * 2 + 255) / 256 * 256;
    unsigned short* rb    = (unsigned short*)p; p += ((size_t)T_ * B_ * V_ * F_ * 2 + 255) / 256 * 256;
    unsigned short* rattb = (unsigned short*)p; p += ((size_t)T_ * B_ * V_ * F_ * 2 + 255) / 256 * 256;

    k_lanes<<<(B_ * L_) / 64, 256, 0, stream>>>(lanes, mask, Wk, bk, Wv, bv, kproj, lsvT, maskb);
    k_qr<<<(T_ * B_ * V_) / 64, 256, 0, stream>>>(vehicles, initial_pos, Wq, bq, Wr, br, qb, rb);
    k_attn<<<4 * B_ * H_, 256, 0, stream>>>(kproj, lsvT, maskb, qb, rb, rattb);
    k_out<<<(T_ * B_ * V_) / 64, 256, 0, stream>>>(rattb, Wc, bc, vehicles, initial_pos, out);
}

// Round 5
// 148.141 us; speedup vs baseline: 3.3728x; 1.1361x over previous
//
#include <hip/hip_runtime.h>
#include <hip/hip_bf16.h>
#include <math.h>

// Problem dims
#define T_ 30
#define B_ 32
#define V_ 32
#define F_ 128
#define L_ 256
#define LF_ 64
#define H_ 8
#define DH_ 16
#define HIST_ 10

typedef __attribute__((ext_vector_type(4))) float floatx4;
typedef __attribute__((ext_vector_type(8))) short shortx8;
typedef __attribute__((ext_vector_type(4))) unsigned short ushortx4;

#define MFMA_BF16(a, b, c) __builtin_amdgcn_mfma_f32_16x16x32_bf16(a, b, c, 0, 0, 0)

__device__ inline unsigned short f2bf_rne(float x) {
    unsigned int u = __builtin_bit_cast(unsigned int, x);
    unsigned int r = (u + 0x7fffu + ((u >> 16) & 1u)) >> 16;
    return (unsigned short)r;
}
__device__ inline unsigned short f2bf_trunc(float x) {
    return (unsigned short)(__builtin_bit_cast(unsigned int, x) >> 16);
}
__device__ inline float bf2f(unsigned short u) {
    return __builtin_bit_cast(float, (unsigned int)u << 16);
}
__device__ inline ushortx4 cvt4(floatx4 a) {
    ushortx4 r;
    r.x = f2bf_rne(a.x); r.y = f2bf_rne(a.y);
    r.z = f2bf_rne(a.z); r.w = f2bf_rne(a.w);
    return r;
}

// ---------- fused projections ----------
// blocks 0..127: lane projections -> kproj bf16 [B*L][128], lsvT bf16 [B][128][256]
//                (pre-masked), maskb fp32
// blocks 128..607: vehicle projections -> qb bf16 (0.25*log2e folded), rb bf16,
//                resid = bf16(veh - ip)
__global__ __launch_bounds__(256, 2) void k_proj(
    const float* __restrict__ lanes, const int* __restrict__ mask,
    const float* __restrict__ veh, const float* __restrict__ ip,
    const float* __restrict__ Wk, const float* __restrict__ bk,
    const float* __restrict__ Wv, const float* __restrict__ bv,
    const float* __restrict__ Wq, const float* __restrict__ bq,
    const float* __restrict__ Wr, const float* __restrict__ br,
    unsigned short* __restrict__ kproj, unsigned short* __restrict__ lsvT,
    float* __restrict__ maskb, unsigned short* __restrict__ qb,
    unsigned short* __restrict__ rb, unsigned short* __restrict__ resid) {
    __shared__ unsigned short smem[32768];   // 64 KB union
    __shared__ float mloc[64];
    int tid = threadIdx.x;

    if (blockIdx.x < 128) {
        // ---- lane projections ----
        unsigned short* WkF = smem;          // [(nt*2+ks)*64+lane][8]
        unsigned short* WvF = smem + 8192;
        int m0 = blockIdx.x * 64;
        int b = m0 >> 8;
        if (tid < 64) {
            int row = m0 + tid;
            int any = 0;
#pragma unroll
            for (int hh = 0; hh < HIST_; ++hh) any |= mask[hh * (B_ * L_) + row];
            float fm = any ? 1.0f : 0.0f;
            maskb[row] = fm;
            mloc[tid] = fm;
        }
        for (int g = tid; g < 1024; g += 256) {
            int frag = g >> 6, l = g & 63, cc = l & 15, qq = l >> 4;
            int nt = frag >> 1, ks = frag & 1;
            int n = nt * 16 + cc, k0 = ks * 32 + qq * 8;
            floatx4 a0 = *(const floatx4*)(Wk + n * LF_ + k0);
            floatx4 a1 = *(const floatx4*)(Wk + n * LF_ + k0 + 4);
            *(ushortx4*)(WkF + g * 8) = cvt4(a0);
            *(ushortx4*)(WkF + g * 8 + 4) = cvt4(a1);
            floatx4 b0 = *(const floatx4*)(Wv + n * LF_ + k0);
            floatx4 b1 = *(const floatx4*)(Wv + n * LF_ + k0 + 4);
            *(ushortx4*)(WvF + g * 8) = cvt4(b0);
            *(ushortx4*)(WvF + g * 8 + 4) = cvt4(b1);
        }
        __syncthreads();
        int lane = tid & 63, w = tid >> 6;
        int c = lane & 15, quad = lane >> 4;
        int mw = m0 + w * 16;
        shortx8 aF[2];
#pragma unroll
        for (int ks = 0; ks < 2; ++ks) {
            const float* xp = lanes + (size_t)(mw + c) * LF_ + ks * 32 + quad * 8;
            floatx4 x0 = *(const floatx4*)(xp);
            floatx4 x1 = *(const floatx4*)(xp + 4);
            ushortx4 lo = cvt4(x0), hi = cvt4(x1);
            shortx8 af;
            af[0]=(short)lo.x; af[1]=(short)lo.y; af[2]=(short)lo.z; af[3]=(short)lo.w;
            af[4]=(short)hi.x; af[5]=(short)hi.y; af[6]=(short)hi.z; af[7]=(short)hi.w;
            aF[ks] = af;
        }
        floatx4 mk = *(const floatx4*)(mloc + w * 16 + quad * 4);
        int lbase = (mw & 255) + quad * 4;
#pragma unroll
        for (int nt = 0; nt < 8; ++nt) {
            floatx4 acck = {0.f, 0.f, 0.f, 0.f}, accv = {0.f, 0.f, 0.f, 0.f};
#pragma unroll
            for (int ks = 0; ks < 2; ++ks) {
                shortx8 bkf = *(const shortx8*)(WkF + ((nt * 2 + ks) * 64 + lane) * 8);
                shortx8 bvf = *(const shortx8*)(WvF + ((nt * 2 + ks) * 64 + lane) * 8);
                acck = MFMA_BF16(aF[ks], bkf, acck);
                accv = MFMA_BF16(aF[ks], bvf, accv);
            }
            int n = nt * 16 + c;
            float bkn = bk[n], bvn = bv[n];
            ushortx4 vout;
#pragma unroll
            for (int reg = 0; reg < 4; ++reg) {
                size_t row = mw + quad * 4 + reg;
                kproj[row * F_ + n] = f2bf_rne(acck[reg] + bkn);
                float xv = accv[reg] + bvn;
                float ls = fminf(xv, 0.f) - log1pf(__expf(-fabsf(xv)));
                vout[reg] = (mk[reg] > 0.5f) ? f2bf_rne(ls) : (unsigned short)0;
            }
            *(ushortx4*)(lsvT + ((size_t)b * F_ + n) * L_ + lbase) = vout;
        }
    } else {
        // ---- vehicle projections ----
        unsigned short* WqF = smem;          // [(nt*4+ks)*64+lane][8]
        unsigned short* WrF = smem + 16384;
        for (int g = tid; g < 2048; g += 256) {
            int frag = g >> 6, l = g & 63, cc = l & 15, qq = l >> 4;
            int nt = frag >> 2, ks = frag & 3;
            int n = nt * 16 + cc, k0 = ks * 32 + qq * 8;
            floatx4 a0 = *(const floatx4*)(Wq + n * F_ + k0);
            floatx4 a1 = *(const floatx4*)(Wq + n * F_ + k0 + 4);
            *(ushortx4*)(WqF + g * 8) = cvt4(a0);
            *(ushortx4*)(WqF + g * 8 + 4) = cvt4(a1);
            floatx4 b0 = *(const floatx4*)(Wr + n * F_ + k0);
            floatx4 b1 = *(const floatx4*)(Wr + n * F_ + k0 + 4);
            *(ushortx4*)(WrF + g * 8) = cvt4(b0);
            *(ushortx4*)(WrF + g * 8 + 4) = cvt4(b1);
        }
        __syncthreads();
        int lane = tid & 63, w = tid >> 6;
        int c = lane & 15, quad = lane >> 4;
        int m0 = (blockIdx.x - 128) * 64 + w * 16;
        shortx8 aF[4];
#pragma unroll
        for (int ks = 0; ks < 4; ++ks) {
            size_t off = (size_t)(m0 + c) * F_ + ks * 32 + quad * 8;
            floatx4 v0 = *(const floatx4*)(veh + off);
            floatx4 v1 = *(const floatx4*)(veh + off + 4);
            floatx4 i0 = *(const floatx4*)(ip + off);
            floatx4 i1 = *(const floatx4*)(ip + off + 4);
            ushortx4 lo = cvt4(v0 + i0), hi = cvt4(v1 + i1);
            shortx8 af;
            af[0]=(short)lo.x; af[1]=(short)lo.y; af[2]=(short)lo.z; af[3]=(short)lo.w;
            af[4]=(short)hi.x; af[5]=(short)hi.y; af[6]=(short)hi.z; af[7]=(short)hi.w;
            aF[ks] = af;
            *(ushortx4*)(resid + off) = cvt4(v0 - i0);
            *(ushortx4*)(resid + off + 4) = cvt4(v1 - i1);
        }
        const float QSCALE = 0.25f * 1.4426950408889634f;  // 1/sqrt(DH) * log2(e)
#pragma unroll
        for (int nt = 0; nt < 8; ++nt) {
            floatx4 accq = {0.f, 0.f, 0.f, 0.f}, accr = {0.f, 0.f, 0.f, 0.f};
#pragma unroll
            for (int ks = 0; ks < 4; ++ks) {
                shortx8 bqf = *(const shortx8*)(WqF + ((nt * 4 + ks) * 64 + lane) * 8);
                shortx8 brf = *(const shortx8*)(WrF + ((nt * 4 + ks) * 64 + lane) * 8);
                accq = MFMA_BF16(aF[ks], bqf, accq);
                accr = MFMA_BF16(aF[ks], brf, accr);
            }
            int n = nt * 16 + c;
            float bqn = bq[n], brn = br[n];
#pragma unroll
            for (int reg = 0; reg < 4; ++reg) {
                size_t row = m0 + quad * 4 + reg;
                qb[row * F_ + n] = f2bf_rne((accq[reg] + bqn) * QSCALE);
                rb[row * F_ + n] = f2bf_rne(accr[reg] + brn);
            }
        }
    }
}

// ---------- MFMA attention ----------
// exp2-domain scores (log2e folded into q); no max-subtract (scores bounded);
// V pre-masked in lsvT; denominator via mask-row MFMA; pE wave-private in
// B-FRAGMENT ORDER: reads are consecutive-lane b128 (conflict-free), writes
// 4-way (was: reads 8-way).
__global__ __launch_bounds__(256, 2) void k_attn(
    const unsigned short* __restrict__ kproj, const unsigned short* __restrict__ lsvT,
    const float* __restrict__ maskb, const unsigned short* __restrict__ qbuf,
    const unsigned short* __restrict__ rbuf, unsigned short* __restrict__ ratt) {
    __shared__ unsigned short kS[256 * 24];     // [l][16d], stride 24
    __shared__ unsigned short vT[16 * 264];     // [d][l], stride 264
    __shared__ unsigned short pE[4 * 4096];     // per-wave frag-order P

    int tid = threadIdx.x;
    int bh = blockIdx.x & 255;
    int tc = blockIdx.x >> 8;
    int h = bh & 7;
    int b = bh >> 3;

    const unsigned short* kbase = kproj + ((size_t)b * L_) * F_ + h * DH_;
#pragma unroll
    for (int it = 0; it < 2; ++it) {
        int id = it * 256 + tid;
        int l = id >> 1, half = id & 1;
        shortx8 kv = *(const shortx8*)(kbase + (size_t)l * F_ + half * 8);
        *(shortx8*)(kS + l * 24 + half * 8) = kv;
    }
    {
        int d = tid >> 4, c16 = tid & 15;
        const unsigned short* vrow = lsvT + ((size_t)b * F_ + h * DH_ + d) * L_ + c16 * 16;
        shortx8 v0 = *(const shortx8*)(vrow);
        shortx8 v1 = *(const shortx8*)(vrow + 8);
        *(shortx8*)(vT + d * 264 + c16 * 16) = v0;
        *(shortx8*)(vT + d * 264 + c16 * 16 + 8) = v1;
    }
    __syncthreads();

    int lane = tid & 63, w = tid >> 6;
    int c = lane & 15, quad = lane >> 4;

    shortx8 kF[16];
#pragma unroll
    for (int lt = 0; lt < 16; ++lt) {
        shortx8 z = {0, 0, 0, 0, 0, 0, 0, 0};
        kF[lt] = (quad < 2) ? *(const shortx8*)(kS + (lt * 16 + c) * 24 + quad * 8) : z;
    }
    shortx8 vF[8];
#pragma unroll
    for (int kk = 0; kk < 8; ++kk)
        vF[kk] = *(const shortx8*)(vT + c * 264 + kk * 32 + quad * 8);
    shortx8 mF[8];
#pragma unroll
    for (int kk = 0; kk < 8; ++kk) {
        const float* mp = maskb + b * L_ + kk * 32 + quad * 8;
        floatx4 ma = *(const floatx4*)(mp);
        floatx4 mb2 = *(const floatx4*)(mp + 4);
        shortx8 mf;
        mf[0]=(short)f2bf_trunc(ma.x); mf[1]=(short)f2bf_trunc(ma.y);
        mf[2]=(short)f2bf_trunc(ma.z); mf[3]=(short)f2bf_trunc(ma.w);
        mf[4]=(short)f2bf_trunc(mb2.x); mf[5]=(short)f2bf_trunc(mb2.y);
        mf[6]=(short)f2bf_trunc(mb2.z); mf[7]=(short)f2bf_trunc(mb2.w);
        mF[kk] = mf;
    }

    unsigned short* pEw = pE + w * 4096;
    // frag-order write slot for this lane (per lt): kk = lt>>1,
    // quadp = (lt&1)*2 + (quad>>1), sub = (quad&1)*4
    int wr_c = c * 8 + (quad & 1) * 4;       // + quadp*128 + kk*512
    int wr_q = (quad >> 1) * 128;
    floatx4 z4 = {0.f, 0.f, 0.f, 0.f};

    for (int mtl = w; mtl < 15; mtl += 4) {
        int mt = tc * 15 + mtl;
        int q0 = mt << 4;
        int t = q0 >> 5, v0 = q0 & 31;
        size_t qrow0 = ((size_t)(t * B_ + b) * V_ + v0 + c) * F_ + h * DH_;

        shortx8 qF = {0, 0, 0, 0, 0, 0, 0, 0};
        if (quad < 2) qF = *(const shortx8*)(qbuf + qrow0 + quad * 8);

#pragma unroll
        for (int lt = 0; lt < 16; ++lt) {
            floatx4 s = MFMA_BF16(kF[lt], qF, z4);  // S^T[l][q], exp2 domain
            ushortx4 ep;
#pragma unroll
            for (int reg = 0; reg < 4; ++reg)
                ep[reg] = f2bf_trunc(__builtin_amdgcn_exp2f(s[reg]));
            // frag-order: addr = (kk*64 + quadp*16 + c)*8 + (quad&1)*4
            *(ushortx4*)(pEw + (lt >> 1) * 512 + (lt & 1) * 256 + wr_q + wr_c) = ep;
        }

        floatx4 cU = z4, cN = z4;
#pragma unroll
        for (int kk = 0; kk < 8; ++kk) {
            shortx8 bP = *(const shortx8*)(pEw + (kk * 64 + lane) * 8);
            cU = MFMA_BF16(vF[kk], bP, cU);
            cN = MFMA_BF16(mF[kk], bP, cN);
        }
        float inv2 = __builtin_amdgcn_rcpf(cN[0]) * 1.4426950408889634f;
        ushortx4 rv = *(const ushortx4*)(rbuf + qrow0 + quad * 4);
        ushortx4 ob;
#pragma unroll
        for (int reg = 0; reg < 4; ++reg) {
            float att = __builtin_amdgcn_exp2f(cU[reg] * inv2);  // e^(U/sum)
            ob[reg] = f2bf_rne(bf2f(rv[reg]) * att);
        }
        *(ushortx4*)(ratt + (((size_t)t * B_ + b) * H_ + h) * (V_ * DH_)
                    + (v0 + c) * DH_ + quad * 4) = ob;
    }
}

// ---------- combine (MFMA): out = ratt@Wc^T + bc + resid ----------
__global__ __launch_bounds__(256, 2) void k_out(
    const unsigned short* __restrict__ ratt, const float* __restrict__ Wc,
    const float* __restrict__ bc, const unsigned short* __restrict__ resid,
    float* __restrict__ out) {
    __shared__ unsigned short WcF[16384];
    int tid = threadIdx.x;
    for (int g = tid; g < 2048; g += 256) {
        int frag = g >> 6, l = g & 63, cc = l & 15, qq = l >> 4;
        int nt = frag >> 2, ks = frag & 3;
        int n = nt * 16 + cc, k0 = ks * 32 + qq * 8;
        floatx4 a0 = *(const floatx4*)(Wc + n * F_ + k0);
        floatx4 a1 = *(const floatx4*)(Wc + n * F_ + k0 + 4);
        *(ushortx4*)(WcF + g * 8) = cvt4(a0);
        *(ushortx4*)(WcF + g * 8 + 4) = cvt4(a1);
    }
    __syncthreads();
    int lane = tid & 63, w = tid >> 6;
    int c = lane & 15, quad = lane >> 4;
    int m0 = blockIdx.x * 64 + w * 16;
    shortx8 aF[4];
#pragma unroll
    for (int ks = 0; ks < 4; ++ks)
        aF[ks] = *(const shortx8*)(ratt + (size_t)(m0 + c) * F_ + ks * 32 + quad * 8);
#pragma unroll
    for (int np = 0; np < 4; ++np) {
        int nt0 = np * 2, nt1 = np * 2 + 1;
        floatx4 acc0 = {0.f, 0.f, 0.f, 0.f}, acc1 = {0.f, 0.f, 0.f, 0.f};
#pragma unroll
        for (int ks = 0; ks < 4; ++ks) {
            shortx8 b0 = *(const shortx8*)(WcF + ((nt0 * 4 + ks) * 64 + lane) * 8);
            shortx8 b1 = *(const shortx8*)(WcF + ((nt1 * 4 + ks) * 64 + lane) * 8);
            acc0 = MFMA_BF16(aF[ks], b0, acc0);
            acc1 = MFMA_BF16(aF[ks], b1, acc1);
        }
        int n0 = nt0 * 16 + c, n1 = nt1 * 16 + c;
        float bc0 = bc[n0], bc1 = bc[n1];
#pragma unroll
        for (int reg = 0; reg < 4; ++reg) {
            size_t row = m0 + quad * 4 + reg;
            size_t o0 = row * F_ + n0, o1 = row * F_ + n1;
            out[o0] = acc0[reg] + bc0 + bf2f(resid[o0]);
            out[o1] = acc1[reg] + bc1 + bf2f(resid[o1]);
        }
    }
}

extern "C" void kernel_launch(void* const* d_in, const int* in_sizes, int n_in,
                              void* d_out, int out_size, void* d_ws, size_t ws_size,
                              hipStream_t stream) {
    const float* vehicles    = (const float*)d_in[0];
    const float* initial_pos = (const float*)d_in[1];
    const float* lanes       = (const float*)d_in[2];
    const int*   mask        = (const int*)d_in[3];
    const float* Wk = (const float*)d_in[4];
    const float* bk = (const float*)d_in[5];
    const float* Wv = (const float*)d_in[6];
    const float* bv = (const float*)d_in[7];
    const float* Wq = (const float*)d_in[8];
    const float* bq = (const float*)d_in[9];
    const float* Wr = (const float*)d_in[10];
    const float* br = (const float*)d_in[11];
    const float* Wc = (const float*)d_in[12];
    const float* bc = (const float*)d_in[13];
    float* out = (float*)d_out;

    char* p = (char*)d_ws;
    float* maskb = (float*)p;                   p += ((B_ * L_ * 4 + 255) / 256) * 256;
    unsigned short* kproj = (unsigned short*)p; p += ((size_t)B_ * L_ * F_ * 2 + 255) / 256 * 256;
    unsigned short* lsvT  = (unsigned short*)p; p += ((size_t)B_ * F_ * L_ * 2 + 255) / 256 * 256;
    unsigned short* qb    = (unsigned short*)p; p += ((size_t)T_ * B_ * V_ * F_ * 2 + 255) / 256 * 256;
    unsigned short* rb    = (unsigned short*)p; p += ((size_t)T_ * B_ * V_ * F_ * 2 + 255) / 256 * 256;
    unsigned short* rattb = (unsigned short*)p; p += ((size_t)T_ * B_ * V_ * F_ * 2 + 255) / 256 * 256;
    unsigned short* resid = (unsigned short*)p; p += ((size_t)T_ * B_ * V_ * F_ * 2 + 255) / 256 * 256;

    k_proj<<<128 + (T_ * B_ * V_) / 64, 256, 0, stream>>>(
        lanes, mask, vehicles, initial_pos, Wk, bk, Wv, bv, Wq, bq, Wr, br,
        kproj, lsvT, maskb, qb, rb, resid);
    k_attn<<<4 * B_ * H_, 256, 0, stream>>>(kproj, lsvT, maskb, qb, rb, rattb);
    k_out<<<(T_ * B_ * V_) / 64, 256, 0, stream>>>(rattb, Wc, bc, resid, out);
}

// Round 6
// 142.971 us; speedup vs baseline: 3.4948x; 1.0362x over previous
//
#include <hip/hip_runtime.h>
#include <hip/hip_bf16.h>
#include <math.h>

// Problem dims
#define T_ 30
#define B_ 32
#define V_ 32
#define F_ 128
#define L_ 256
#define LF_ 64
#define H_ 8
#define DH_ 16
#define HIST_ 10

typedef __attribute__((ext_vector_type(4))) float floatx4;
typedef __attribute__((ext_vector_type(8))) short shortx8;
typedef __attribute__((ext_vector_type(4))) unsigned short ushortx4;

#define MFMA_BF16(a, b, c) __builtin_amdgcn_mfma_f32_16x16x32_bf16(a, b, c, 0, 0, 0)

__device__ inline unsigned short f2bf_rne(float x) {
    unsigned int u = __builtin_bit_cast(unsigned int, x);
    unsigned int r = (u + 0x7fffu + ((u >> 16) & 1u)) >> 16;
    return (unsigned short)r;
}
__device__ inline unsigned short f2bf_trunc(float x) {
    return (unsigned short)(__builtin_bit_cast(unsigned int, x) >> 16);
}
__device__ inline float bf2f(unsigned short u) {
    return __builtin_bit_cast(float, (unsigned int)u << 16);
}
__device__ inline ushortx4 cvt4(floatx4 a) {
    ushortx4 r;
    r.x = f2bf_rne(a.x); r.y = f2bf_rne(a.y);
    r.z = f2bf_rne(a.z); r.w = f2bf_rne(a.w);
    return r;
}

// ---------- fused projections ----------
// blocks 0..127: lane projections -> kproj bf16 [B*L][128], lsvT bf16 [B][128][256]
//                (pre-masked), maskb fp32
// blocks 128..607: vehicle projections -> qhm/rhm bf16 HEAD-MAJOR
//                [(b*H+h)][t][v][16] (q has 0.25*log2e folded), resid bf16
__global__ __launch_bounds__(256, 2) void k_proj(
    const float* __restrict__ lanes, const int* __restrict__ mask,
    const float* __restrict__ veh, const float* __restrict__ ip,
    const float* __restrict__ Wk, const float* __restrict__ bk,
    const float* __restrict__ Wv, const float* __restrict__ bv,
    const float* __restrict__ Wq, const float* __restrict__ bq,
    const float* __restrict__ Wr, const float* __restrict__ br,
    unsigned short* __restrict__ kproj, unsigned short* __restrict__ lsvT,
    float* __restrict__ maskb, unsigned short* __restrict__ qhm,
    unsigned short* __restrict__ rhm, unsigned short* __restrict__ resid) {
    __shared__ unsigned short smem[32768];   // 64 KB union
    __shared__ float mloc[64];
    int tid = threadIdx.x;

    if (blockIdx.x < 128) {
        // ---- lane projections ----
        unsigned short* WkF = smem;          // [(nt*2+ks)*64+lane][8]
        unsigned short* WvF = smem + 8192;
        int m0 = blockIdx.x * 64;
        int b = m0 >> 8;
        if (tid < 64) {
            int row = m0 + tid;
            int any = 0;
#pragma unroll
            for (int hh = 0; hh < HIST_; ++hh) any |= mask[hh * (B_ * L_) + row];
            float fm = any ? 1.0f : 0.0f;
            maskb[row] = fm;
            mloc[tid] = fm;
        }
        for (int g = tid; g < 1024; g += 256) {
            int frag = g >> 6, l = g & 63, cc = l & 15, qq = l >> 4;
            int nt = frag >> 1, ks = frag & 1;
            int n = nt * 16 + cc, k0 = ks * 32 + qq * 8;
            floatx4 a0 = *(const floatx4*)(Wk + n * LF_ + k0);
            floatx4 a1 = *(const floatx4*)(Wk + n * LF_ + k0 + 4);
            *(ushortx4*)(WkF + g * 8) = cvt4(a0);
            *(ushortx4*)(WkF + g * 8 + 4) = cvt4(a1);
            floatx4 b0 = *(const floatx4*)(Wv + n * LF_ + k0);
            floatx4 b1 = *(const floatx4*)(Wv + n * LF_ + k0 + 4);
            *(ushortx4*)(WvF + g * 8) = cvt4(b0);
            *(ushortx4*)(WvF + g * 8 + 4) = cvt4(b1);
        }
        __syncthreads();
        int lane = tid & 63, w = tid >> 6;
        int c = lane & 15, quad = lane >> 4;
        int mw = m0 + w * 16;
        shortx8 aF[2];
#pragma unroll
        for (int ks = 0; ks < 2; ++ks) {
            const float* xp = lanes + (size_t)(mw + c) * LF_ + ks * 32 + quad * 8;
            floatx4 x0 = *(const floatx4*)(xp);
            floatx4 x1 = *(const floatx4*)(xp + 4);
            ushortx4 lo = cvt4(x0), hi = cvt4(x1);
            shortx8 af;
            af[0]=(short)lo.x; af[1]=(short)lo.y; af[2]=(short)lo.z; af[3]=(short)lo.w;
            af[4]=(short)hi.x; af[5]=(short)hi.y; af[6]=(short)hi.z; af[7]=(short)hi.w;
            aF[ks] = af;
        }
        floatx4 mk = *(const floatx4*)(mloc + w * 16 + quad * 4);
        int lbase = (mw & 255) + quad * 4;
#pragma unroll
        for (int nt = 0; nt < 8; ++nt) {
            floatx4 acck = {0.f, 0.f, 0.f, 0.f}, accv = {0.f, 0.f, 0.f, 0.f};
#pragma unroll
            for (int ks = 0; ks < 2; ++ks) {
                shortx8 bkf = *(const shortx8*)(WkF + ((nt * 2 + ks) * 64 + lane) * 8);
                shortx8 bvf = *(const shortx8*)(WvF + ((nt * 2 + ks) * 64 + lane) * 8);
                acck = MFMA_BF16(aF[ks], bkf, acck);
                accv = MFMA_BF16(aF[ks], bvf, accv);
            }
            int n = nt * 16 + c;
            float bkn = bk[n], bvn = bv[n];
            ushortx4 vout;
#pragma unroll
            for (int reg = 0; reg < 4; ++reg) {
                size_t row = mw + quad * 4 + reg;
                kproj[row * F_ + n] = f2bf_rne(acck[reg] + bkn);
                float xv = accv[reg] + bvn;
                float ls = fminf(xv, 0.f) - log1pf(__expf(-fabsf(xv)));
                vout[reg] = (mk[reg] > 0.5f) ? f2bf_rne(ls) : (unsigned short)0;
            }
            *(ushortx4*)(lsvT + ((size_t)b * F_ + n) * L_ + lbase) = vout;
        }
    } else {
        // ---- vehicle projections ----
        unsigned short* WqF = smem;          // [(nt*4+ks)*64+lane][8]
        unsigned short* WrF = smem + 16384;
        for (int g = tid; g < 2048; g += 256) {
            int frag = g >> 6, l = g & 63, cc = l & 15, qq = l >> 4;
            int nt = frag >> 2, ks = frag & 3;
            int n = nt * 16 + cc, k0 = ks * 32 + qq * 8;
            floatx4 a0 = *(const floatx4*)(Wq + n * F_ + k0);
            floatx4 a1 = *(const floatx4*)(Wq + n * F_ + k0 + 4);
            *(ushortx4*)(WqF + g * 8) = cvt4(a0);
            *(ushortx4*)(WqF + g * 8 + 4) = cvt4(a1);
            floatx4 b0 = *(const floatx4*)(Wr + n * F_ + k0);
            floatx4 b1 = *(const floatx4*)(Wr + n * F_ + k0 + 4);
            *(ushortx4*)(WrF + g * 8) = cvt4(b0);
            *(ushortx4*)(WrF + g * 8 + 4) = cvt4(b1);
        }
        __syncthreads();
        int lane = tid & 63, w = tid >> 6;
        int c = lane & 15, quad = lane >> 4;
        int m0 = (blockIdx.x - 128) * 64 + w * 16;
        shortx8 aF[4];
#pragma unroll
        for (int ks = 0; ks < 4; ++ks) {
            size_t off = (size_t)(m0 + c) * F_ + ks * 32 + quad * 8;
            floatx4 v0 = *(const floatx4*)(veh + off);
            floatx4 v1 = *(const floatx4*)(veh + off + 4);
            floatx4 i0 = *(const floatx4*)(ip + off);
            floatx4 i1 = *(const floatx4*)(ip + off + 4);
            ushortx4 lo = cvt4(v0 + i0), hi = cvt4(v1 + i1);
            shortx8 af;
            af[0]=(short)lo.x; af[1]=(short)lo.y; af[2]=(short)lo.z; af[3]=(short)lo.w;
            af[4]=(short)hi.x; af[5]=(short)hi.y; af[6]=(short)hi.z; af[7]=(short)hi.w;
            aF[ks] = af;
            *(ushortx4*)(resid + off) = cvt4(v0 - i0);
            *(ushortx4*)(resid + off + 4) = cvt4(v1 - i1);
        }
        const float QSCALE = 0.25f * 1.4426950408889634f;  // 1/sqrt(DH) * log2(e)
#pragma unroll
        for (int nt = 0; nt < 8; ++nt) {
            floatx4 accq = {0.f, 0.f, 0.f, 0.f}, accr = {0.f, 0.f, 0.f, 0.f};
#pragma unroll
            for (int ks = 0; ks < 4; ++ks) {
                shortx8 bqf = *(const shortx8*)(WqF + ((nt * 4 + ks) * 64 + lane) * 8);
                shortx8 brf = *(const shortx8*)(WrF + ((nt * 4 + ks) * 64 + lane) * 8);
                accq = MFMA_BF16(aF[ks], bqf, accq);
                accr = MFMA_BF16(aF[ks], brf, accr);
            }
            int n = nt * 16 + c;   // h = nt, dh = c
            float bqn = bq[n], brn = br[n];
#pragma unroll
            for (int reg = 0; reg < 4; ++reg) {
                int row = m0 + quad * 4 + reg;
                int t = row >> 10, rem = row & 1023;
                int b = rem >> 5, v = rem & 31;
                // head-major: [(b*8+nt)*30+t][v][dh=c]
                size_t hidx = ((size_t)((b * 8 + nt) * 30 + t) << 9) + (v << 4) + c;
                qhm[hidx] = f2bf_rne((accq[reg] + bqn) * QSCALE);
                rhm[hidx] = f2bf_rne(accr[reg] + brn);
            }
        }
    }
}

// ---------- MFMA attention ----------
// tc=2: 512 blocks (2/CU, one-shot residency), each stages K/V once and runs
// 30 query-tiles. exp2-domain scores; V pre-masked; denominator via mask-row
// MFMA; pE wave-private in B-fragment order (conflict-light). q/r head-major
// -> per-tile loads are one contiguous 512B region.
__global__ __launch_bounds__(256, 2) void k_attn(
    const unsigned short* __restrict__ kproj, const unsigned short* __restrict__ lsvT,
    const float* __restrict__ maskb, const unsigned short* __restrict__ qhm,
    const unsigned short* __restrict__ rhm, unsigned short* __restrict__ ratt) {
    __shared__ unsigned short kS[256 * 24];     // [l][16d], stride 24
    __shared__ unsigned short vT[16 * 264];     // [d][l], stride 264
    __shared__ unsigned short pE[4 * 4096];     // per-wave frag-order P

    int tid = threadIdx.x;
    int bh = blockIdx.x & 255;
    int tc = blockIdx.x >> 8;        // 0..1
    int h = bh & 7;
    int b = bh >> 3;

    const unsigned short* kbase = kproj + ((size_t)b * L_) * F_ + h * DH_;
#pragma unroll
    for (int it = 0; it < 2; ++it) {
        int id = it * 256 + tid;
        int l = id >> 1, half = id & 1;
        shortx8 kv = *(const shortx8*)(kbase + (size_t)l * F_ + half * 8);
        *(shortx8*)(kS + l * 24 + half * 8) = kv;
    }
    {
        int d = tid >> 4, c16 = tid & 15;
        const unsigned short* vrow = lsvT + ((size_t)b * F_ + h * DH_ + d) * L_ + c16 * 16;
        shortx8 v0 = *(const shortx8*)(vrow);
        shortx8 v1 = *(const shortx8*)(vrow + 8);
        *(shortx8*)(vT + d * 264 + c16 * 16) = v0;
        *(shortx8*)(vT + d * 264 + c16 * 16 + 8) = v1;
    }
    __syncthreads();

    int lane = tid & 63, w = tid >> 6;
    int c = lane & 15, quad = lane >> 4;

    shortx8 kF[16];
#pragma unroll
    for (int lt = 0; lt < 16; ++lt) {
        shortx8 z = {0, 0, 0, 0, 0, 0, 0, 0};
        kF[lt] = (quad < 2) ? *(const shortx8*)(kS + (lt * 16 + c) * 24 + quad * 8) : z;
    }
    shortx8 vF[8];
#pragma unroll
    for (int kk = 0; kk < 8; ++kk)
        vF[kk] = *(const shortx8*)(vT + c * 264 + kk * 32 + quad * 8);
    shortx8 mF[8];
#pragma unroll
    for (int kk = 0; kk < 8; ++kk) {
        const float* mp = maskb + b * L_ + kk * 32 + quad * 8;
        floatx4 ma = *(const floatx4*)(mp);
        floatx4 mb2 = *(const floatx4*)(mp + 4);
        shortx8 mf;
        mf[0]=(short)f2bf_trunc(ma.x); mf[1]=(short)f2bf_trunc(ma.y);
        mf[2]=(short)f2bf_trunc(ma.z); mf[3]=(short)f2bf_trunc(ma.w);
        mf[4]=(short)f2bf_trunc(mb2.x); mf[5]=(short)f2bf_trunc(mb2.y);
        mf[6]=(short)f2bf_trunc(mb2.z); mf[7]=(short)f2bf_trunc(mb2.w);
        mF[kk] = mf;
    }

    const unsigned short* qhead = qhm + ((size_t)(b * 8 + h) * 30) * 512;
    const unsigned short* rhead = rhm + ((size_t)(b * 8 + h) * 30) * 512;

    unsigned short* pEw = pE + w * 4096;
    // frag-order write slot: addr = (kk*64 + quadp*16 + c)*8 + (quad&1)*4
    int wr_c = c * 8 + (quad & 1) * 4;
    int wr_q = (quad >> 1) * 128;
    floatx4 z4 = {0.f, 0.f, 0.f, 0.f};

    for (int mtl = w; mtl < 30; mtl += 4) {
        int mt = tc * 30 + mtl;              // 0..59
        int t = mt >> 1, v0 = (mt & 1) * 16;
        size_t qtile = (size_t)t * 512 + v0 * 16;   // contiguous 512B region

        shortx8 qF = {0, 0, 0, 0, 0, 0, 0, 0};
        if (quad < 2) qF = *(const shortx8*)(qhead + qtile + c * 16 + quad * 8);

#pragma unroll
        for (int lt = 0; lt < 16; ++lt) {
            floatx4 s = MFMA_BF16(kF[lt], qF, z4);  // S^T[l][q], exp2 domain
            ushortx4 ep;
#pragma unroll
            for (int reg = 0; reg < 4; ++reg)
                ep[reg] = f2bf_trunc(__builtin_amdgcn_exp2f(s[reg]));
            *(ushortx4*)(pEw + (lt >> 1) * 512 + (lt & 1) * 256 + wr_q + wr_c) = ep;
        }

        floatx4 cU = z4, cN = z4;
#pragma unroll
        for (int kk = 0; kk < 8; ++kk) {
            shortx8 bP = *(const shortx8*)(pEw + (kk * 64 + lane) * 8);
            cU = MFMA_BF16(vF[kk], bP, cU);
            cN = MFMA_BF16(mF[kk], bP, cN);
        }
        float inv2 = __builtin_amdgcn_rcpf(cN[0]) * 1.4426950408889634f;
        ushortx4 rv = *(const ushortx4*)(rhead + qtile + c * 16 + quad * 4);
        ushortx4 ob;
#pragma unroll
        for (int reg = 0; reg < 4; ++reg) {
            float att = __builtin_amdgcn_exp2f(cU[reg] * inv2);  // e^(U/sum)
            ob[reg] = f2bf_rne(bf2f(rv[reg]) * att);
        }
        *(ushortx4*)(ratt + (((size_t)t * B_ + b) * H_ + h) * (V_ * DH_)
                    + (v0 + c) * DH_ + quad * 4) = ob;
    }
}

// ---------- combine (MFMA): out = ratt@Wc^T + bc + resid ----------
__global__ __launch_bounds__(256, 2) void k_out(
    const unsigned short* __restrict__ ratt, const float* __restrict__ Wc,
    const float* __restrict__ bc, const unsigned short* __restrict__ resid,
    float* __restrict__ out) {
    __shared__ unsigned short WcF[16384];
    int tid = threadIdx.x;
    for (int g = tid; g < 2048; g += 256) {
        int frag = g >> 6, l = g & 63, cc = l & 15, qq = l >> 4;
        int nt = frag >> 2, ks = frag & 3;
        int n = nt * 16 + cc, k0 = ks * 32 + qq * 8;
        floatx4 a0 = *(const floatx4*)(Wc + n * F_ + k0);
        floatx4 a1 = *(const floatx4*)(Wc + n * F_ + k0 + 4);
        *(ushortx4*)(WcF + g * 8) = cvt4(a0);
        *(ushortx4*)(WcF + g * 8 + 4) = cvt4(a1);
    }
    __syncthreads();
    int lane = tid & 63, w = tid >> 6;
    int c = lane & 15, quad = lane >> 4;
    int m0 = blockIdx.x * 64 + w * 16;
    shortx8 aF[4];
#pragma unroll
    for (int ks = 0; ks < 4; ++ks)
        aF[ks] = *(const shortx8*)(ratt + (size_t)(m0 + c) * F_ + ks * 32 + quad * 8);
#pragma unroll
    for (int np = 0; np < 4; ++np) {
        int nt0 = np * 2, nt1 = np * 2 + 1;
        floatx4 acc0 = {0.f, 0.f, 0.f, 0.f}, acc1 = {0.f, 0.f, 0.f, 0.f};
#pragma unroll
        for (int ks = 0; ks < 4; ++ks) {
            shortx8 b0 = *(const shortx8*)(WcF + ((nt0 * 4 + ks) * 64 + lane) * 8);
            shortx8 b1 = *(const shortx8*)(WcF + ((nt1 * 4 + ks) * 64 + lane) * 8);
            acc0 = MFMA_BF16(aF[ks], b0, acc0);
            acc1 = MFMA_BF16(aF[ks], b1, acc1);
        }
        int n0 = nt0 * 16 + c, n1 = nt1 * 16 + c;
        float bc0 = bc[n0], bc1 = bc[n1];
#pragma unroll
        for (int reg = 0; reg < 4; ++reg) {
            size_t row = m0 + quad * 4 + reg;
            size_t o0 = row * F_ + n0, o1 = row * F_ + n1;
            out[o0] = acc0[reg] + bc0 + bf2f(resid[o0]);
            out[o1] = acc1[reg] + bc1 + bf2f(resid[o1]);
        }
    }
}

extern "C" void kernel_launch(void* const* d_in, const int* in_sizes, int n_in,
                              void* d_out, int out_size, void* d_ws, size_t ws_size,
                              hipStream_t stream) {
    const float* vehicles    = (const float*)d_in[0];
    const float* initial_pos = (const float*)d_in[1];
    const float* lanes       = (const float*)d_in[2];
    const int*   mask        = (const int*)d_in[3];
    const float* Wk = (const float*)d_in[4];
    const float* bk = (const float*)d_in[5];
    const float* Wv = (const float*)d_in[6];
    const float* bv = (const float*)d_in[7];
    const float* Wq = (const float*)d_in[8];
    const float* bq = (const float*)d_in[9];
    const float* Wr = (const float*)d_in[10];
    const float* br = (const float*)d_in[11];
    const float* Wc = (const float*)d_in[12];
    const float* bc = (const float*)d_in[13];
    float* out = (float*)d_out;

    char* p = (char*)d_ws;
    float* maskb = (float*)p;                   p += ((B_ * L_ * 4 + 255) / 256) * 256;
    unsigned short* kproj = (unsigned short*)p; p += ((size_t)B_ * L_ * F_ * 2 + 255) / 256 * 256;
    unsigned short* lsvT  = (unsigned short*)p; p += ((size_t)B_ * F_ * L_ * 2 + 255) / 256 * 256;
    unsigned short* qhm   = (unsigned short*)p; p += ((size_t)T_ * B_ * V_ * F_ * 2 + 255) / 256 * 256;
    unsigned short* rhm   = (unsigned short*)p; p += ((size_t)T_ * B_ * V_ * F_ * 2 + 255) / 256 * 256;
    unsigned short* rattb = (unsigned short*)p; p += ((size_t)T_ * B_ * V_ * F_ * 2 + 255) / 256 * 256;
    unsigned short* resid = (unsigned short*)p; p += ((size_t)T_ * B_ * V_ * F_ * 2 + 255) / 256 * 256;

    k_proj<<<128 + (T_ * B_ * V_) / 64, 256, 0, stream>>>(
        lanes, mask, vehicles, initial_pos, Wk, bk, Wv, bv, Wq, bq, Wr, br,
        kproj, lsvT, maskb, qhm, rhm, resid);
    k_attn<<<2 * B_ * H_, 256, 0, stream>>>(kproj, lsvT, maskb, qhm, rhm, rattb);
    k_out<<<(T_ * B_ * V_) / 64, 256, 0, stream>>>(rattb, Wc, bc, resid, out);
}